// Round 3
// baseline (822.632 us; speedup 1.0000x reference)
//
#include <hip/hip_runtime.h>

// Problem constants
#define Tn 512
#define Sn 512
#define Bn 8
#define Dn 512
#define Hn 8
#define HDn 64
#define Ln 8
#define Fn 2048
#define SCALE 0.125f

typedef short short8 __attribute__((ext_vector_type(8)));
typedef float floatx4 __attribute__((ext_vector_type(4)));

__device__ __forceinline__ unsigned short f2b(float f) {
    unsigned int u = __float_as_uint(f);
    u += 0x7FFFu + ((u >> 16) & 1u);   // round-to-nearest-even
    return (unsigned short)(u >> 16);
}

// ---------------------------------------------------------------------------
// Prep: (T,B,D) f32 -> (B*T, D) bf16 rows
__global__ __launch_bounds__(256) void to_rows_bf16(const float* __restrict__ in,
                                                    unsigned short* __restrict__ out, int T_) {
    size_t n = (size_t)blockIdx.x * 256 + threadIdx.x;
    size_t total = (size_t)T_ * Bn * Dn;
    if (n >= total) return;
    int d = (int)(n & (Dn - 1));
    size_t rt = n >> 9;              // Dn = 512
    int t = (int)(rt % T_);
    int b = (int)(rt / T_);
    out[n] = f2b(in[((size_t)t * Bn + b) * Dn + d]);
}

// ---------------------------------------------------------------------------
// One-shot weight conversion into a packed bf16 arena + concatenated qkv bias.
// Arena layout (units of 256K = 1<<18 elems): [0..3):qkv  [3]:sao  [4..7):cain
// [7]:cao  [8..12):lin1  [12..16):lin2  [16]:rel(32K)
__global__ __launch_bounds__(256) void conv_all(
    const float* __restrict__ qw, const float* __restrict__ kw, const float* __restrict__ vw,
    const float* __restrict__ sow, const float* __restrict__ ciw, const float* __restrict__ cow,
    const float* __restrict__ l1w, const float* __restrict__ l2w, const float* __restrict__ rel,
    const float* __restrict__ qbias, const float* __restrict__ kbias, const float* __restrict__ vbias,
    unsigned short* __restrict__ wall, float* __restrict__ bqkv) {
    const int Q = 1 << 18;
    const int total = 16 * Q + Ln * HDn * HDn;   // 4227072
    int i = blockIdx.x * 256 + threadIdx.x;
    if (i < total) {
        int seg = i >> 18, r = i & (Q - 1);
        float v;
        if (seg < 3)       v = (seg == 0 ? qw : (seg == 1 ? kw : vw))[r];
        else if (seg == 3) v = sow[r];
        else if (seg < 7)  v = ciw[(size_t)(seg - 4) * Q + r];
        else if (seg == 7) v = cow[r];
        else if (seg < 12) v = l1w[(size_t)(seg - 8) * Q + r];
        else if (seg < 16) v = l2w[(size_t)(seg - 12) * Q + r];
        else               v = rel[r];
        wall[i] = f2b(v);
    }
    int j = i - total;
    if (j >= 0 && j < 3 * Dn)
        bqkv[j] = (j < Dn ? qbias[j] : (j < 2 * Dn ? kbias[j - Dn] : vbias[j - 2 * Dn]));
}

// ---------------------------------------------------------------------------
// Shared epilogue: scatter one 16x16 C tile per (mt,nt) per mode.
// mode 0: f32 row-major   1: bf16 row-major   2: bf16 heads (B,H,T,HD)
// mode 3: bf16 headsT (B,H,HD,T)
// mode 4: fused qkv split: gn<512->Cv heads, <1024->Cv2 heads, else Cv3 headsT
// mode 5: fused kv  split: gn<512->Cv heads, else Cv2 headsT
__device__ __forceinline__ void c_scatter(
    floatx4 v, int gm, int gn, size_t coff, int ldc, float alpha, float bb,
    int mode, int relu, int Tp, void* Cv, void* Cv2, void* Cv3) {
    for (int r = 0; r < 4; ++r) {
        float val = v[r] * alpha + bb;
        if (relu) val = fmaxf(val, 0.0f);
        int m = gm + r;
        if (mode == 0) {
            ((float*)Cv)[coff + (size_t)m * ldc + gn] = val;
        } else if (mode == 1) {
            ((unsigned short*)Cv)[coff + (size_t)m * ldc + gn] = f2b(val);
        } else if (mode == 2) {
            int bq = m / Tp, t = m - bq * Tp;
            ((unsigned short*)Cv)[(((size_t)(bq * Hn + (gn >> 6)) * Tp + t) << 6) + (gn & 63)] = f2b(val);
        } else if (mode == 3) {
            int bq = m / Tp, t = m - bq * Tp;
            ((unsigned short*)Cv)[((size_t)(bq * Hn + (gn >> 6)) * 64 + (gn & 63)) * Tp + t] = f2b(val);
        } else if (mode == 4) {
            int sel = gn >> 9, g2 = gn & 511;
            int bq = m / Tp, t = m - bq * Tp;
            int hh = g2 >> 6, dd = g2 & 63;
            if (sel == 0)
                ((unsigned short*)Cv)[(((size_t)(bq * Hn + hh) * Tp + t) << 6) + dd] = f2b(val);
            else if (sel == 1)
                ((unsigned short*)Cv2)[(((size_t)(bq * Hn + hh) * Tp + t) << 6) + dd] = f2b(val);
            else
                ((unsigned short*)Cv3)[((size_t)(bq * Hn + hh) * 64 + dd) * Tp + t] = f2b(val);
        } else { // mode 5
            int sel = gn >> 9, g2 = gn & 511;
            int bq = m / Tp, t = m - bq * Tp;
            int hh = g2 >> 6, dd = g2 & 63;
            if (sel == 0)
                ((unsigned short*)Cv)[(((size_t)(bq * Hn + hh) * Tp + t) << 6) + dd] = f2b(val);
            else
                ((unsigned short*)Cv2)[((size_t)(bq * Hn + hh) * 64 + dd) * Tp + t] = f2b(val);
        }
    }
}

// ---------------------------------------------------------------------------
// Batched bf16 MFMA GEMM, 64x64 block tile (heavily-batched attn GEMMs).
// K-loop unroll(2) for load ILP.
__global__ __launch_bounds__(256) void gemm_bf16(
    const unsigned short* __restrict__ A, const unsigned short* __restrict__ W,
    const float* __restrict__ bias, void* __restrict__ Cv, void* __restrict__ Cv2,
    void* __restrict__ Cv3,
    int M, int N, int K, int lda, int ldw, int ldc,
    long sA1, long sA2, long sW1, long sW2, long sC1, long sC2, int zdiv,
    float alpha, int mode, int relu, int Tp) {
    int z = blockIdx.z;
    int z1 = z / zdiv, z2 = z - z1 * zdiv;
    const unsigned short* Ab = A + (size_t)z1 * sA1 + (size_t)z2 * sA2;
    const unsigned short* Wb = W + (size_t)z1 * sW1 + (size_t)z2 * sW2;
    size_t coff = (size_t)z1 * sC1 + (size_t)z2 * sC2;
    int tid = threadIdx.x;
    int lane = tid & 63, wave = tid >> 6;
    int wm = wave & 1, wn = wave >> 1;
    int l16 = lane & 15, quad = lane >> 4;
    int m0 = blockIdx.y * 64 + wm * 32;
    int n0 = blockIdx.x * 64 + wn * 32;

    floatx4 acc00 = {0,0,0,0}, acc01 = {0,0,0,0}, acc10 = {0,0,0,0}, acc11 = {0,0,0,0};
    const unsigned short* a0p = Ab + (size_t)(m0 + l16) * lda + quad * 8;
    const unsigned short* a1p = a0p + (size_t)16 * lda;
    const unsigned short* b0p = Wb + (size_t)(n0 + l16) * ldw + quad * 8;
    const unsigned short* b1p = b0p + (size_t)16 * ldw;

#pragma unroll 2
    for (int kk = 0; kk < K; kk += 32) {
        short8 a0 = *(const short8*)(a0p + kk);
        short8 a1 = *(const short8*)(a1p + kk);
        short8 b0 = *(const short8*)(b0p + kk);
        short8 b1 = *(const short8*)(b1p + kk);
        acc00 = __builtin_amdgcn_mfma_f32_16x16x32_bf16(a0, b0, acc00, 0, 0, 0);
        acc01 = __builtin_amdgcn_mfma_f32_16x16x32_bf16(a0, b1, acc01, 0, 0, 0);
        acc10 = __builtin_amdgcn_mfma_f32_16x16x32_bf16(a1, b0, acc10, 0, 0, 0);
        acc11 = __builtin_amdgcn_mfma_f32_16x16x32_bf16(a1, b1, acc11, 0, 0, 0);
    }
    floatx4 accs[2][2] = {{acc00, acc01}, {acc10, acc11}};
    for (int mt = 0; mt < 2; ++mt)
        for (int nt = 0; nt < 2; ++nt) {
            int gn = n0 + nt * 16 + l16;
            float bb = bias ? bias[gn] : 0.0f;
            c_scatter(accs[mt][nt], m0 + mt * 16 + quad * 4, gn, coff, ldc,
                      alpha, bb, mode, relu, Tp, Cv, Cv2, Cv3);
        }
}

// ---------------------------------------------------------------------------
// bf16 MFMA GEMM, templated tile: block = 2x2 waves, each wave MT*16 x NT*16.
// Block tile = (MT*32) x (NT*32). No waves/EU cap (R5 lesson).
template <int MT, int NT>
__global__ __launch_bounds__(256) void gemmT_bf16(
    const unsigned short* __restrict__ A, const unsigned short* __restrict__ W,
    const float* __restrict__ bias, void* __restrict__ Cv, void* __restrict__ Cv2,
    void* __restrict__ Cv3,
    int K, int lda, int ldw, int ldc,
    float alpha, int mode, int relu, int Tp) {
    int tid = threadIdx.x;
    int lane = tid & 63, wave = tid >> 6;
    int wm = wave & 1, wn = wave >> 1;
    int l16 = lane & 15, quad = lane >> 4;
    int m0 = blockIdx.y * (MT * 32) + wm * (MT * 16);
    int n0 = blockIdx.x * (NT * 32) + wn * (NT * 16);

    floatx4 acc[MT][NT] = {};
    const unsigned short* ap = A + (size_t)(m0 + l16) * lda + quad * 8;
    const unsigned short* bp = W + (size_t)(n0 + l16) * ldw + quad * 8;

    for (int kk = 0; kk < K; kk += 32) {
        short8 a[MT], b[NT];
#pragma unroll
        for (int mt = 0; mt < MT; ++mt)
            a[mt] = *(const short8*)(ap + (size_t)mt * 16 * lda + kk);
#pragma unroll
        for (int nt = 0; nt < NT; ++nt)
            b[nt] = *(const short8*)(bp + (size_t)nt * 16 * ldw + kk);
#pragma unroll
        for (int mt = 0; mt < MT; ++mt)
#pragma unroll
            for (int nt = 0; nt < NT; ++nt)
                acc[mt][nt] = __builtin_amdgcn_mfma_f32_16x16x32_bf16(a[mt], b[nt], acc[mt][nt], 0, 0, 0);
    }
    for (int mt = 0; mt < MT; ++mt)
        for (int nt = 0; nt < NT; ++nt) {
            int gn = n0 + nt * 16 + l16;
            float bb = bias ? bias[gn] : 0.0f;
            c_scatter(acc[mt][nt], m0 + mt * 16 + quad * 4, gn, 0, ldc,
                      alpha, bb, mode, relu, Tp, Cv, Cv2, Cv3);
        }
}

// ---------------------------------------------------------------------------
// Fused scores+softmax -> bf16 probs, transposed-MFMA.
// Block = 256 threads = 4 waves, same 16 rows i of one (b,h); wave w owns
// j in [w*128,(w+1)*128).
// R10 structure (register-resident, clobber-free):
//  * NO "memory" clobbers anywhere -- bare s_waitcnt asm + sched_barrier(0)
//    (rule #18) so kf/uf/sacc stay in SSA registers across waits.
//  * __launch_bounds__(256,2) for EM: VGPR budget 256 (LDS caps occupancy at
//    2 blocks/CU anyway, so the extra registers are free).
//  * l-loop FULLY unrolled; ALL u fragments (uf[NL][2]) + pad words hoisted to
//    the prologue -> the only in-loop VMEM is the 8 stage loads, so the
//    counted vmcnt is exact: vmcnt(8) leaves exactly stage(l+1) in flight.
//  * em slices staged via global_load_lds into wave-private 8KB quarters,
//    double-buffered; global source pre-swizzled so LDS reads are ~2-way.
template <int NL, bool EM>
__global__ __launch_bounds__(256, EM ? 2 : 4) void relsoft(
    const unsigned short* __restrict__ uR,   // (B,H,NL,T,HD) bf16
    const unsigned short* __restrict__ kB,   // (B,H,T,HD) bf16
    const float* __restrict__ em,            // (B,NL,T,T) f32 or null
    const unsigned char* __restrict__ pad,   // (B,T,T) or null
    unsigned short* __restrict__ P) {        // (B,H,T,T) bf16
    int id = blockIdx.x;
    // XCD swizzle: h-siblings (same b,it) share id%8 -> same XCD L2 for em reuse
    int c = id & 7, h = (id >> 3) & 7, g = id >> 6;
    int u = g * 8 + c;                 // 0..255
    int b = u >> 5, it = u & 31;
    int bh = b * Hn + h;
    int wave = threadIdx.x >> 6, lane = threadIdx.x & 63;
    int l16 = lane & 15, quad = lane >> 4;
    int i = it * 16 + l16;

    const int JC = Tn / 64;            // 8 j-chunks of 16 per wave

    // em LDS: [2 bufs][4 waves][512 slots x 16B] = 64 KB (f32, no precision loss)
    __shared__ float emS[EM ? 2 * 4 * 512 * 4 : 4];
    __shared__ float redm[4][16];
    __shared__ float reds[4][16];

    const float* emRow = nullptr;
    if constexpr (EM)
        emRow = em + ((size_t)b * NL * Tn + (size_t)it * 16) * Tn;

    // Stage em slice l into buf: wave-private 512 slots (16 rows x 32 cols of 16B).
    // Slot s holds em[row ii = s>>5][col16 = wave*32 + ((s&31) ^ (ii&7))].
    auto stage = [&](int l, int buf) {
        const float* rowb = emRow + (size_t)l * Tn * Tn;
        float* wb = emS + (size_t)(buf * 4 + wave) * 512 * 4;
#pragma unroll
        for (int k = 0; k < 8; ++k) {
            int s = k * 64 + lane;
            int ii = s >> 5, c32 = s & 31;
            const float* gp = rowb + (size_t)ii * Tn + ((wave * 32) + (c32 ^ (ii & 7))) * 4;
            __builtin_amdgcn_global_load_lds(
                (const __attribute__((address_space(1))) void*)gp,
                (__attribute__((address_space(3))) void*)(wb + k * 64 * 4),
                16, 0, 0);
        }
    };

    // ---- prologue: ALL scalar/vector register loads BEFORE the stages so the
    // first counted vmcnt retires them and nothing else issues in the loop.
    unsigned int puf[JC] = {};
    if constexpr (EM) {
#pragma unroll
        for (int jc = 0; jc < JC; ++jc)
            puf[jc] = *(const unsigned int*)(pad + ((size_t)b * Tn + i) * Tn +
                                             (wave * JC + jc) * 16 + quad * 4);
    }

    const unsigned short* kp0 = kB + (size_t)bh * Tn * HDn + (size_t)l16 * HDn + quad * 8;
    short8 kf[JC][2];
#pragma unroll
    for (int jc = 0; jc < JC; ++jc) {
        const unsigned short* kp = kp0 + (size_t)(wave * JC + jc) * 16 * HDn;
        kf[jc][0] = *(const short8*)(kp);
        kf[jc][1] = *(const short8*)(kp + 32);
    }

    const unsigned short* ub = uR + (size_t)bh * NL * Tn * HDn + (size_t)i * HDn + quad * 8;
    short8 uf[NL][2];
#pragma unroll
    for (int l = 0; l < NL; ++l) {
        uf[l][0] = *(const short8*)(ub + (size_t)l * Tn * HDn);
        uf[l][1] = *(const short8*)(ub + (size_t)l * Tn * HDn + 32);
    }

    if constexpr (EM) {
        stage(0, 0);
        if (NL > 1) stage(1, 1);
    }

    floatx4 sacc[JC] = {};
#pragma unroll
    for (int l = 0; l < NL; ++l) {
        if constexpr (EM) {
            // stage(l) complete; stage(l+1)'s 8 loads stay in flight (T4:
            // never drain to 0 mid-loop). Last iter: drain all.
            if (l + 1 < NL) asm volatile("s_waitcnt vmcnt(8)");
            else            asm volatile("s_waitcnt vmcnt(0)");
            __builtin_amdgcn_sched_barrier(0);
        }
        const float* rb = emS + (size_t)((l & 1) * 4 + wave) * 512 * 4;
#pragma unroll
        for (int jc = 0; jc < JC; ++jc) {
            floatx4 gacc = {0, 0, 0, 0};
            gacc = __builtin_amdgcn_mfma_f32_16x16x32_bf16(kf[jc][0], uf[l][0], gacc, 0, 0, 0);
            gacc = __builtin_amdgcn_mfma_f32_16x16x32_bf16(kf[jc][1], uf[l][1], gacc, 0, 0, 0);
            if constexpr (EM) {
                int q = l16 * 32 + ((jc * 4 + quad) ^ (l16 & 7));
                floatx4 e4 = *(const floatx4*)(rb + (size_t)q * 4);
                sacc[jc] += e4 * gacc;
            } else {
                sacc[jc] = gacc;
            }
        }
        if constexpr (EM) {
            if (l + 2 < NL) {
                // all ds_reads of buf(l) done before re-staging into it
                asm volatile("s_waitcnt lgkmcnt(0)");
                __builtin_amdgcn_sched_barrier(0);
                stage(l + 2, l & 1);
            }
        }
    }

    // scale + pad mask + per-wave row max
    float mx = -3.0e38f;
#pragma unroll
    for (int jc = 0; jc < JC; ++jc) {
        floatx4 v = sacc[jc] * SCALE;
        if constexpr (EM) {
            unsigned int pu = puf[jc];
            if (pu) {
                if (pu & 0x000000FFu) v[0] = -1.0e9f;
                if (pu & 0x0000FF00u) v[1] = -1.0e9f;
                if (pu & 0x00FF0000u) v[2] = -1.0e9f;
                if (pu & 0xFF000000u) v[3] = -1.0e9f;
            }
        }
        sacc[jc] = v;
        mx = fmaxf(mx, fmaxf(fmaxf(v[0], v[1]), fmaxf(v[2], v[3])));
    }
    mx = fmaxf(mx, __shfl_xor(mx, 16, 64));
    mx = fmaxf(mx, __shfl_xor(mx, 32, 64));

    if (quad == 0) redm[wave][l16] = mx;
    __syncthreads();
    mx = fmaxf(fmaxf(redm[0][l16], redm[1][l16]), fmaxf(redm[2][l16], redm[3][l16]));

    float sum = 0.0f;
#pragma unroll
    for (int jc = 0; jc < JC; ++jc) {
        floatx4 v = sacc[jc];
        v[0] = __expf(v[0] - mx); v[1] = __expf(v[1] - mx);
        v[2] = __expf(v[2] - mx); v[3] = __expf(v[3] - mx);
        sacc[jc] = v;
        sum += v[0] + v[1] + v[2] + v[3];
    }
    sum += __shfl_xor(sum, 16, 64);
    sum += __shfl_xor(sum, 32, 64);
    if (quad == 0) reds[wave][l16] = sum;
    __syncthreads();
    sum = (reds[0][l16] + reds[1][l16]) + (reds[2][l16] + reds[3][l16]);
    float inv = 1.0f / sum;

    unsigned short* prow = P + (size_t)bh * Tn * Tn + (size_t)i * Tn;
#pragma unroll
    for (int jc = 0; jc < JC; ++jc) {
        int jt = wave * JC + jc;
        floatx4 v = sacc[jc];
        ushort4 o;
        o.x = f2b(v[0] * inv); o.y = f2b(v[1] * inv);
        o.z = f2b(v[2] * inv); o.w = f2b(v[3] * inv);
        *(ushort4*)(prow + jt * 16 + quad * 4) = o;
    }
}

// ---------------------------------------------------------------------------
// LayerNorm over D=512: out = (a[row] + b2[row] - mean)/sqrt(var+eps)*s + bb
__global__ __launch_bounds__(256) void ln_kernel(
    const float* __restrict__ a, int a_trans, const float* __restrict__ b2,
    const float* __restrict__ s, const float* __restrict__ bb,
    float* __restrict__ outF, int out_trans, unsigned short* __restrict__ outB) {
    int row = blockIdx.x;            // b*Tn + t
    int b = row >> 9, t = row & (Tn - 1);
    int tid = threadIdx.x;
    size_t ia = a_trans ? ((size_t)(t * Bn + b)) * Dn : (size_t)row * Dn;
    size_t ir = (size_t)row * Dn;
    float x0 = a[ia + tid];
    float x1 = a[ia + tid + 256];
    if (b2) { x0 += b2[ir + tid]; x1 += b2[ir + tid + 256]; }
    float s1 = x0 + x1, s2 = x0 * x0 + x1 * x1;
    for (int off = 32; off; off >>= 1) {
        s1 += __shfl_xor(s1, off, 64);
        s2 += __shfl_xor(s2, off, 64);
    }
    __shared__ float red[2][4];
    int wave = tid >> 6, lane = tid & 63;
    if (lane == 0) { red[0][wave] = s1; red[1][wave] = s2; }
    __syncthreads();
    float ts1 = red[0][0] + red[0][1] + red[0][2] + red[0][3];
    float ts2 = red[1][0] + red[1][1] + red[1][2] + red[1][3];
    float mean = ts1 * (1.0f / Dn);
    float var = ts2 * (1.0f / Dn) - mean * mean;
    float rs = rsqrtf(var + 1e-5f);
    float y0 = (x0 - mean) * rs * s[tid] + bb[tid];
    float y1 = (x1 - mean) * rs * s[tid + 256] + bb[tid + 256];
    size_t io = out_trans ? ((size_t)(t * Bn + b)) * Dn : ir;
    if (outF) { outF[io + tid] = y0; outF[io + tid + 256] = y1; }
    if (outB) { outB[ir + tid] = f2b(y0); outB[ir + tid + 256] = f2b(y1); }
}

// ---------------------------------------------------------------------------
extern "C" void kernel_launch(void* const* d_in, const int* in_sizes, int n_in,
                              void* d_out, int out_size, void* d_ws, size_t ws_size,
                              hipStream_t stream) {
    const float* tgt      = (const float*)d_in[0];
    const float* em       = (const float*)d_in[1];
    const unsigned char* pad = (const unsigned char*)d_in[2];
    const float* memr     = (const float*)d_in[3];
    const float* sa_q_w   = (const float*)d_in[4];
    const float* sa_q_b   = (const float*)d_in[5];
    const float* sa_k_w   = (const float*)d_in[6];
    const float* sa_k_b   = (const float*)d_in[7];
    const float* sa_v_w   = (const float*)d_in[8];
    const float* sa_v_b   = (const float*)d_in[9];
    const float* sa_rel   = (const float*)d_in[10];
    const float* sa_out_w = (const float*)d_in[11];
    const float* sa_out_b = (const float*)d_in[12];
    const float* ca_in_w  = (const float*)d_in[13];
    const float* ca_in_b  = (const float*)d_in[14];
    const float* ca_out_w = (const float*)d_in[15];
    const float* ca_out_b = (const float*)d_in[16];
    const float* lin1_w   = (const float*)d_in[17];
    const float* lin1_b   = (const float*)d_in[18];
    const float* lin2_w   = (const float*)d_in[19];
    const float* lin2_b   = (const float*)d_in[20];
    const float* ln1_s    = (const float*)d_in[21];
    const float* ln1_b    = (const float*)d_in[22];
    const float* ln2_s    = (const float*)d_in[23];
    const float* ln2_b    = (const float*)d_in[24];
    const float* ln3_s    = (const float*)d_in[25];
    const float* ln3_b    = (const float*)d_in[26];

    const size_t BT = (size_t)Bn * Tn;   // 4096
    const size_t Q  = 1 << 18;           // 256K elems

    // ---- workspace carve-out ----
    char* ws = (char*)d_ws;
    size_t off = 0;
    auto alloc = [&](size_t bytes) -> char* {
        char* p = ws + off;
        off += (bytes + 255) & ~(size_t)255;
        return p;
    };
    unsigned short* xb   = (unsigned short*)alloc(BT * Dn * 2);
    unsigned short* mb   = (unsigned short*)alloc(BT * Dn * 2);
    unsigned short* wall = (unsigned short*)alloc((16 * Q + Ln * HDn * HDn) * 2);
    float*          bqkv = (float*)alloc(3 * Dn * 4);
    unsigned short* qb   = (unsigned short*)alloc(BT * Dn * 2);          // (B,H,T,HD)
    unsigned short* kb   = (unsigned short*)alloc(BT * Dn * 2);          // (B,H,T,HD)
    unsigned short* vtb  = (unsigned short*)alloc(BT * Dn * 2);          // (B,H,HD,T)
    unsigned short* ur   = (unsigned short*)alloc((size_t)Bn * Hn * Ln * Tn * HDn * 2);
    unsigned short* pb   = (unsigned short*)alloc((size_t)Bn * Hn * Tn * Tn * 2); // 32MB probs
    unsigned short* ob   = (unsigned short*)alloc(BT * Dn * 2);
    float*          t2f  = (float*)alloc(BT * Dn * 4);
    float*          x1f  = (float*)alloc(BT * Dn * 4);
    unsigned short* x1b  = (unsigned short*)alloc(BT * Dn * 2);
    float*          x2f  = (float*)alloc(BT * Dn * 4);
    unsigned short* x2b  = (unsigned short*)alloc(BT * Dn * 2);
    unsigned short* hid  = (unsigned short*)alloc(BT * Fn * 2);
    (void)ws_size; (void)in_sizes; (void)n_in; (void)out_size;

    // arena views
    unsigned short* wqkv = wall;
    unsigned short* wsao = wall + 3 * Q;
    unsigned short* wcain = wall + 4 * Q;
    unsigned short* wcao = wall + 7 * Q;
    unsigned short* wlin1 = wall + 8 * Q;
    unsigned short* wlin2 = wall + 12 * Q;
    unsigned short* wrel = wall + 16 * Q;

    auto gemm = [&](const unsigned short* A, const unsigned short* W, const float* bias,
                    void* C, void* C2, void* C3, int M, int N, int K, int lda, int ldw, int ldc,
                    long sA1, long sA2, long sW1, long sW2, long sC1, long sC2,
                    int zdiv, int batches, float alpha, int mode, int relu, int Tp) {
        dim3 g(N / 64, M / 64, batches);
        gemm_bf16<<<g, 256, 0, stream>>>(A, W, bias, C, C2, C3, M, N, K, lda, ldw, ldc,
                                         sA1, sA2, sW1, sW2, sC1, sC2, zdiv,
                                         alpha, mode, relu, Tp);
    };
    // 128x128 tile
    auto gemmBig = [&](const unsigned short* A, const unsigned short* W, const float* bias,
                       void* C, void* C2, void* C3, int M, int N, int K,
                       int lda, int ldw, int ldc, float alpha, int mode, int relu, int Tp) {
        dim3 g(N / 128, M / 128, 1);
        gemmT_bf16<4, 4><<<g, 256, 0, stream>>>(A, W, bias, C, C2, C3, K, lda, ldw, ldc,
                                                alpha, mode, relu, Tp);
    };
    // 128x64 tile (N=512 cases -> 256 blocks = 1/CU)
    auto gemmMed = [&](const unsigned short* A, const unsigned short* W, const float* bias,
                       void* C, void* C2, void* C3, int M, int N, int K,
                       int lda, int ldw, int ldc, float alpha, int mode, int relu, int Tp) {
        dim3 g(N / 64, M / 128, 1);
        gemmT_bf16<4, 2><<<g, 256, 0, stream>>>(A, W, bias, C, C2, C3, K, lda, ldw, ldc,
                                                alpha, mode, relu, Tp);
    };

    // ---- prep ----
    to_rows_bf16<<<dim3((BT * Dn + 255) / 256), 256, 0, stream>>>(tgt, xb, Tn);
    to_rows_bf16<<<dim3((BT * Dn + 255) / 256), 256, 0, stream>>>(memr, mb, Sn);
    conv_all<<<dim3((16 * Q + Ln * HDn * HDn + 3 * Dn + 255) / 256), 256, 0, stream>>>(
        sa_q_w, sa_k_w, sa_v_w, sa_out_w, ca_in_w, ca_out_w, lin1_w, lin2_w, sa_rel,
        sa_q_b, sa_k_b, sa_v_b, wall, bqkv);

    // ---- self-attention ----
    // fused q,k,v: (B,H,T,HD) x2 + v as (B,H,HD,T)
    gemmBig(xb, wqkv, bqkv, qb, kb, vtb, (int)BT, 3 * Dn, Dn, Dn, Dn, 0, 1.0f, 4, 0, Tn);
    // uR[b,h,l] = q[b,h] @ R_l^T  (batched over B*H*L)
    gemm(qb, wrel, nullptr, ur, nullptr, nullptr, Tn, HDn, HDn, HDn, HDn, HDn,
         (long)Tn * HDn, 0, 0, (long)HDn * HDn, (long)Ln * Tn * HDn, (long)Tn * HDn,
         Ln, Bn * Hn * Ln, 1.0f, 1, 0, 0);
    // fused rel-scores + em + scale + pad + softmax -> bf16 P
    relsoft<Ln, true><<<dim3(2048), 256, 0, stream>>>(ur, kb, em, pad, pb);
    // O = P @ V
    gemm(pb, vtb, nullptr, ob, nullptr, nullptr, Tn, HDn, Tn, Tn, Tn, Dn,
         (long)Hn * Tn * Tn, (long)Tn * Tn, (long)Hn * HDn * Tn, (long)HDn * Tn,
         (long)Tn * Dn, 64, Hn, Bn * Hn, 1.0f, 1, 0, 0);
    gemmMed(ob, wsao, sa_out_b, t2f, nullptr, nullptr, (int)BT, Dn, Dn, Dn, Dn, Dn,
            1.0f, 0, 0, 0);
    ln_kernel<<<dim3((int)BT), 256, 0, stream>>>(tgt, 1, t2f, ln1_s, ln1_b, x1f, 0, x1b);

    // ---- cross-attention ----
    gemmMed(x1b, wcain, ca_in_b, qb, nullptr, nullptr, (int)BT, Dn, Dn, Dn, Dn, 0,
            1.0f, 2, 0, Tn);
    // fused k,v from memory
    gemmBig(mb, wcain + (size_t)Dn * Dn, ca_in_b + Dn, kb, vtb, nullptr, (int)BT, 2 * Dn, Dn,
            Dn, Dn, 0, 1.0f, 5, 0, Sn);
    // fused qk^T + scale + softmax -> bf16 P
    relsoft<1, false><<<dim3(2048), 256, 0, stream>>>(qb, kb, nullptr, nullptr, pb);
    gemm(pb, vtb, nullptr, ob, nullptr, nullptr, Tn, HDn, Sn, Sn, Sn, Dn,
         (long)Hn * Tn * Sn, (long)Tn * Sn, (long)Hn * HDn * Sn, (long)HDn * Sn,
         (long)Tn * Dn, 64, Hn, Bn * Hn, 1.0f, 1, 0, 0);
    gemmMed(ob, wcao, ca_out_b, t2f, nullptr, nullptr, (int)BT, Dn, Dn, Dn, Dn, Dn,
            1.0f, 0, 0, 0);
    ln_kernel<<<dim3((int)BT), 256, 0, stream>>>(x1f, 0, t2f, ln2_s, ln2_b, x2f, 0, x2b);

    // ---- FFN ----
    gemmBig(x2b, wlin1, lin1_b, hid, nullptr, nullptr, (int)BT, Fn, Dn, Dn, Dn, Fn,
            1.0f, 1, 1, 0);
    gemmMed(hid, wlin2, lin2_b, t2f, nullptr, nullptr, (int)BT, Dn, Fn, Fn, Fn, Dn,
            1.0f, 0, 0, 0);
    ln_kernel<<<dim3((int)BT), 256, 0, stream>>>(x2f, 0, t2f, ln3_s, ln3_b, (float*)d_out, 1, nullptr);
}

// Round 4
// 641.657 us; speedup vs baseline: 1.2820x; 1.2820x over previous
//
#include <hip/hip_runtime.h>

// Problem constants
#define Tn 512
#define Sn 512
#define Bn 8
#define Dn 512
#define Hn 8
#define HDn 64
#define Ln 8
#define Fn 2048
#define SCALE 0.125f

typedef short short8 __attribute__((ext_vector_type(8)));
typedef float floatx4 __attribute__((ext_vector_type(4)));

__device__ __forceinline__ unsigned short f2b(float f) {
    unsigned int u = __float_as_uint(f);
    u += 0x7FFFu + ((u >> 16) & 1u);   // round-to-nearest-even
    return (unsigned short)(u >> 16);
}

// ---------------------------------------------------------------------------
// Prep: (T,B,D) f32 -> (B*T, D) bf16 rows
__global__ __launch_bounds__(256) void to_rows_bf16(const float* __restrict__ in,
                                                    unsigned short* __restrict__ out, int T_) {
    size_t n = (size_t)blockIdx.x * 256 + threadIdx.x;
    size_t total = (size_t)T_ * Bn * Dn;
    if (n >= total) return;
    int d = (int)(n & (Dn - 1));
    size_t rt = n >> 9;              // Dn = 512
    int t = (int)(rt % T_);
    int b = (int)(rt / T_);
    out[n] = f2b(in[((size_t)t * Bn + b) * Dn + d]);
}

// ---------------------------------------------------------------------------
// One-shot weight conversion into a packed bf16 arena + concatenated qkv bias.
// Arena layout (units of 256K = 1<<18 elems): [0..3):qkv  [3]:sao  [4..7):cain
// [7]:cao  [8..12):lin1  [12..16):lin2  [16]:rel(32K)
__global__ __launch_bounds__(256) void conv_all(
    const float* __restrict__ qw, const float* __restrict__ kw, const float* __restrict__ vw,
    const float* __restrict__ sow, const float* __restrict__ ciw, const float* __restrict__ cow,
    const float* __restrict__ l1w, const float* __restrict__ l2w, const float* __restrict__ rel,
    const float* __restrict__ qbias, const float* __restrict__ kbias, const float* __restrict__ vbias,
    unsigned short* __restrict__ wall, float* __restrict__ bqkv) {
    const int Q = 1 << 18;
    const int total = 16 * Q + Ln * HDn * HDn;   // 4227072
    int i = blockIdx.x * 256 + threadIdx.x;
    if (i < total) {
        int seg = i >> 18, r = i & (Q - 1);
        float v;
        if (seg < 3)       v = (seg == 0 ? qw : (seg == 1 ? kw : vw))[r];
        else if (seg == 3) v = sow[r];
        else if (seg < 7)  v = ciw[(size_t)(seg - 4) * Q + r];
        else if (seg == 7) v = cow[r];
        else if (seg < 12) v = l1w[(size_t)(seg - 8) * Q + r];
        else if (seg < 16) v = l2w[(size_t)(seg - 12) * Q + r];
        else               v = rel[r];
        wall[i] = f2b(v);
    }
    int j = i - total;
    if (j >= 0 && j < 3 * Dn)
        bqkv[j] = (j < Dn ? qbias[j] : (j < 2 * Dn ? kbias[j - Dn] : vbias[j - 2 * Dn]));
}

// ---------------------------------------------------------------------------
// Shared epilogue: scatter one 16x16 C tile per (mt,nt) per mode.
// mode 0: f32 row-major   1: bf16 row-major   2: bf16 heads (B,H,T,HD)
// mode 3: bf16 headsT (B,H,HD,T)
// mode 4: fused qkv split: gn<512->Cv heads, <1024->Cv2 heads, else Cv3 headsT
// mode 5: fused kv  split: gn<512->Cv heads, else Cv2 headsT
__device__ __forceinline__ void c_scatter(
    floatx4 v, int gm, int gn, size_t coff, int ldc, float alpha, float bb,
    int mode, int relu, int Tp, void* Cv, void* Cv2, void* Cv3) {
    for (int r = 0; r < 4; ++r) {
        float val = v[r] * alpha + bb;
        if (relu) val = fmaxf(val, 0.0f);
        int m = gm + r;
        if (mode == 0) {
            ((float*)Cv)[coff + (size_t)m * ldc + gn] = val;
        } else if (mode == 1) {
            ((unsigned short*)Cv)[coff + (size_t)m * ldc + gn] = f2b(val);
        } else if (mode == 2) {
            int bq = m / Tp, t = m - bq * Tp;
            ((unsigned short*)Cv)[(((size_t)(bq * Hn + (gn >> 6)) * Tp + t) << 6) + (gn & 63)] = f2b(val);
        } else if (mode == 3) {
            int bq = m / Tp, t = m - bq * Tp;
            ((unsigned short*)Cv)[((size_t)(bq * Hn + (gn >> 6)) * 64 + (gn & 63)) * Tp + t] = f2b(val);
        } else if (mode == 4) {
            int sel = gn >> 9, g2 = gn & 511;
            int bq = m / Tp, t = m - bq * Tp;
            int hh = g2 >> 6, dd = g2 & 63;
            if (sel == 0)
                ((unsigned short*)Cv)[(((size_t)(bq * Hn + hh) * Tp + t) << 6) + dd] = f2b(val);
            else if (sel == 1)
                ((unsigned short*)Cv2)[(((size_t)(bq * Hn + hh) * Tp + t) << 6) + dd] = f2b(val);
            else
                ((unsigned short*)Cv3)[((size_t)(bq * Hn + hh) * 64 + dd) * Tp + t] = f2b(val);
        } else { // mode 5
            int sel = gn >> 9, g2 = gn & 511;
            int bq = m / Tp, t = m - bq * Tp;
            int hh = g2 >> 6, dd = g2 & 63;
            if (sel == 0)
                ((unsigned short*)Cv)[(((size_t)(bq * Hn + hh) * Tp + t) << 6) + dd] = f2b(val);
            else
                ((unsigned short*)Cv2)[((size_t)(bq * Hn + hh) * 64 + dd) * Tp + t] = f2b(val);
        }
    }
}

// ---------------------------------------------------------------------------
// Batched bf16 MFMA GEMM, 64x64 block tile (heavily-batched attn GEMMs).
__global__ __launch_bounds__(256) void gemm_bf16(
    const unsigned short* __restrict__ A, const unsigned short* __restrict__ W,
    const float* __restrict__ bias, void* __restrict__ Cv, void* __restrict__ Cv2,
    void* __restrict__ Cv3,
    int M, int N, int K, int lda, int ldw, int ldc,
    long sA1, long sA2, long sW1, long sW2, long sC1, long sC2, int zdiv,
    float alpha, int mode, int relu, int Tp) {
    int z = blockIdx.z;
    int z1 = z / zdiv, z2 = z - z1 * zdiv;
    const unsigned short* Ab = A + (size_t)z1 * sA1 + (size_t)z2 * sA2;
    const unsigned short* Wb = W + (size_t)z1 * sW1 + (size_t)z2 * sW2;
    size_t coff = (size_t)z1 * sC1 + (size_t)z2 * sC2;
    int tid = threadIdx.x;
    int lane = tid & 63, wave = tid >> 6;
    int wm = wave & 1, wn = wave >> 1;
    int l16 = lane & 15, quad = lane >> 4;
    int m0 = blockIdx.y * 64 + wm * 32;
    int n0 = blockIdx.x * 64 + wn * 32;

    floatx4 acc00 = {0,0,0,0}, acc01 = {0,0,0,0}, acc10 = {0,0,0,0}, acc11 = {0,0,0,0};
    const unsigned short* a0p = Ab + (size_t)(m0 + l16) * lda + quad * 8;
    const unsigned short* a1p = a0p + (size_t)16 * lda;
    const unsigned short* b0p = Wb + (size_t)(n0 + l16) * ldw + quad * 8;
    const unsigned short* b1p = b0p + (size_t)16 * ldw;

#pragma unroll 2
    for (int kk = 0; kk < K; kk += 32) {
        short8 a0 = *(const short8*)(a0p + kk);
        short8 a1 = *(const short8*)(a1p + kk);
        short8 b0 = *(const short8*)(b0p + kk);
        short8 b1 = *(const short8*)(b1p + kk);
        acc00 = __builtin_amdgcn_mfma_f32_16x16x32_bf16(a0, b0, acc00, 0, 0, 0);
        acc01 = __builtin_amdgcn_mfma_f32_16x16x32_bf16(a0, b1, acc01, 0, 0, 0);
        acc10 = __builtin_amdgcn_mfma_f32_16x16x32_bf16(a1, b0, acc10, 0, 0, 0);
        acc11 = __builtin_amdgcn_mfma_f32_16x16x32_bf16(a1, b1, acc11, 0, 0, 0);
    }
    floatx4 accs[2][2] = {{acc00, acc01}, {acc10, acc11}};
    for (int mt = 0; mt < 2; ++mt)
        for (int nt = 0; nt < 2; ++nt) {
            int gn = n0 + nt * 16 + l16;
            float bb = bias ? bias[gn] : 0.0f;
            c_scatter(accs[mt][nt], m0 + mt * 16 + quad * 4, gn, coff, ldc,
                      alpha, bb, mode, relu, Tp, Cv, Cv2, Cv3);
        }
}

// ---------------------------------------------------------------------------
// bf16 MFMA GEMM, templated tile: block = 2x2 waves, each wave MT*16 x NT*16.
template <int MT, int NT>
__global__ __launch_bounds__(256) void gemmT_bf16(
    const unsigned short* __restrict__ A, const unsigned short* __restrict__ W,
    const float* __restrict__ bias, void* __restrict__ Cv, void* __restrict__ Cv2,
    void* __restrict__ Cv3,
    int K, int lda, int ldw, int ldc,
    float alpha, int mode, int relu, int Tp) {
    int tid = threadIdx.x;
    int lane = tid & 63, wave = tid >> 6;
    int wm = wave & 1, wn = wave >> 1;
    int l16 = lane & 15, quad = lane >> 4;
    int m0 = blockIdx.y * (MT * 32) + wm * (MT * 16);
    int n0 = blockIdx.x * (NT * 32) + wn * (NT * 16);

    floatx4 acc[MT][NT] = {};
    const unsigned short* ap = A + (size_t)(m0 + l16) * lda + quad * 8;
    const unsigned short* bp = W + (size_t)(n0 + l16) * ldw + quad * 8;

    for (int kk = 0; kk < K; kk += 32) {
        short8 a[MT], b[NT];
#pragma unroll
        for (int mt = 0; mt < MT; ++mt)
            a[mt] = *(const short8*)(ap + (size_t)mt * 16 * lda + kk);
#pragma unroll
        for (int nt = 0; nt < NT; ++nt)
            b[nt] = *(const short8*)(bp + (size_t)nt * 16 * ldw + kk);
#pragma unroll
        for (int mt = 0; mt < MT; ++mt)
#pragma unroll
            for (int nt = 0; nt < NT; ++nt)
                acc[mt][nt] = __builtin_amdgcn_mfma_f32_16x16x32_bf16(a[mt], b[nt], acc[mt][nt], 0, 0, 0);
    }
    for (int mt = 0; mt < MT; ++mt)
        for (int nt = 0; nt < NT; ++nt) {
            int gn = n0 + nt * 16 + l16;
            float bb = bias ? bias[gn] : 0.0f;
            c_scatter(acc[mt][nt], m0 + mt * 16 + quad * 4, gn, 0, ldc,
                      alpha, bb, mode, relu, Tp, Cv, Cv2, Cv3);
        }
}

// ---------------------------------------------------------------------------
// R11: fused rel-scores + em + scale + pad + softmax for SELF-ATTENTION.
// Grid 256 = (b, it): one block owns one 16-row i-tile, ALL 8 heads, full
// j=512 (softmax block-local). 512 threads = 8 waves; wave w owns j in
// [w*64, w*64+64) = 4 jc-chunks of 16.
//
// Loop: h-PAIRS outer (kf for the pair stays in 64 VGPR, loaded ONCE per
// pair, not per l); l inner with R1-proven double-buffered global_load_lds
// staging of f32 em (2 x 32 KB LDS). em is staged 4x per block; pass 0 from
// HBM, passes 1-3 hit this CU's XCD L2 / L3 (all passes run on the SAME CU).
// This removes the old 8x h-sibling L2 re-read (512 MB -> ~64 MB + local
// re-reads) and amortizes every stage step over 620+ cyc of MFMA.
//
// Per-lane live set: kf 64 + sacc 32 + emr 16 + uf 16 + misc ~ 150 VGPR ->
// fits the 256 budget of __launch_bounds__(512, 2); NO unroll of l/hp, so
// no R3-style spill explosion (watch FETCH/WRITE for scratch).
__global__ __launch_bounds__(512, 2) void relsoft_em(
    const unsigned short* __restrict__ uR,   // (B,H,L,T,HD) bf16
    const unsigned short* __restrict__ kB,   // (B,H,T,HD) bf16
    const float* __restrict__ em,            // (B,L,T,T) f32
    const unsigned char* __restrict__ pad,   // (B,T,T)
    unsigned short* __restrict__ P) {        // (B,H,T,T) bf16
    int b = blockIdx.x >> 5, it = blockIdx.x & 31;
    int tid = threadIdx.x;
    int wave = tid >> 6, lane = tid & 63;
    int l16 = lane & 15, quad = lane >> 4;
    int i = it * 16 + l16;

    // em LDS: 2 bufs x (16 rows x 128 granules of 16B) = 2 x 32 KB
    __shared__ float emS[2 * 8192];
    __shared__ float redm[2][8][16];
    __shared__ float reds[2][8][16];

    // Stage slice (step&7) into buf (step&1). 2048 granules, 4 per thread.
    // LDS slot s (row is=s>>7, slot-granule gs=s&127) holds em granule
    // colg = (gs&~7) | ((gs&7) ^ (is&7))  -> XOR-swizzle so the read
    // (16 lanes same granule-col, different rows) is 2-way (free).
    auto stage = [&](int step) {
        int l = step & 7, buf = step & 1;
        const float* rowb = em + (((size_t)b * Ln + l) * Tn + (size_t)it * 16) * Tn;
#pragma unroll
        for (int k = 0; k < 4; ++k) {
            int s = k * 512 + wave * 64 + lane;
            int is = s >> 7, gs = s & 127;
            int colg = (gs & 120) | ((gs & 7) ^ (is & 7));
            const float* gp = rowb + (size_t)is * Tn + colg * 4;
            __builtin_amdgcn_global_load_lds(
                (const __attribute__((address_space(1))) void*)gp,
                (__attribute__((address_space(3))) void*)(emS + (size_t)buf * 8192 +
                                                         (size_t)(k * 512 + wave * 64) * 4),
                16, 0, 0);
        }
    };

    // pad words: h-invariant, load once
    unsigned int puf[4];
#pragma unroll
    for (int jc = 0; jc < 4; ++jc)
        puf[jc] = *(const unsigned int*)(pad + ((size_t)b * Tn + i) * Tn +
                                         wave * 64 + jc * 16 + quad * 4);

    stage(0);

#pragma clang loop unroll(disable)
    for (int hp = 0; hp < 4; ++hp) {
        int h0 = hp * 2;
        // kf for the pair: resident across the whole l loop
        short8 kf[2][4][2];
#pragma unroll
        for (int hh = 0; hh < 2; ++hh)
#pragma unroll
            for (int jc = 0; jc < 4; ++jc) {
                const unsigned short* kp = kB + (((size_t)(b * Hn + h0 + hh) * Tn) +
                                                wave * 64 + jc * 16 + l16) * HDn + quad * 8;
                kf[hh][jc][0] = *(const short8*)(kp);
                kf[hh][jc][1] = *(const short8*)(kp + 32);
            }
        floatx4 sacc[2][4] = {};

#pragma clang loop unroll(disable)
        for (int l = 0; l < Ln; ++l) {
            int step = hp * 8 + l;
            int buf = l & 1;
            // stage(step) (issued last iteration / prologue) must be complete
            asm volatile("s_waitcnt vmcnt(0)");
            __builtin_amdgcn_sched_barrier(0);
            __syncthreads();                 // all waves' stage parts visible
            if (step + 1 < 32) stage(step + 1);   // into buf^1 (free since l-1)

            // em granules: h-invariant -> read once per (l, jc), reuse both heads
            const float* rb = emS + (size_t)buf * 8192;
            floatx4 emr[4];
#pragma unroll
            for (int jc = 0; jc < 4; ++jc) {
                int gg = wave * 16 + jc * 4 + quad;
                int gsw = (gg & 120) | ((gg & 7) ^ (l16 & 7));
                emr[jc] = *(const floatx4*)(rb + (size_t)(l16 * 128 + gsw) * 4);
            }
            const unsigned short* up = uR + ((((size_t)(b * Hn + h0) * Ln + l) * Tn) + i) * HDn + quad * 8;
            short8 u0a = *(const short8*)(up);
            short8 u0b = *(const short8*)(up + 32);
            short8 u1a = *(const short8*)(up + (size_t)Ln * Tn * HDn);
            short8 u1b = *(const short8*)(up + (size_t)Ln * Tn * HDn + 32);
#pragma unroll
            for (int jc = 0; jc < 4; ++jc) {
                floatx4 g0 = {0, 0, 0, 0};
                g0 = __builtin_amdgcn_mfma_f32_16x16x32_bf16(kf[0][jc][0], u0a, g0, 0, 0, 0);
                g0 = __builtin_amdgcn_mfma_f32_16x16x32_bf16(kf[0][jc][1], u0b, g0, 0, 0, 0);
                sacc[0][jc] += emr[jc] * g0;
                floatx4 g1 = {0, 0, 0, 0};
                g1 = __builtin_amdgcn_mfma_f32_16x16x32_bf16(kf[1][jc][0], u1a, g1, 0, 0, 0);
                g1 = __builtin_amdgcn_mfma_f32_16x16x32_bf16(kf[1][jc][1], u1b, g1, 0, 0, 0);
                sacc[1][jc] += emr[jc] * g1;
            }
        }

        // ---- softmax epilogue for the pair ----
#pragma unroll
        for (int hh = 0; hh < 2; ++hh) {
            float mx = -3.0e38f;
#pragma unroll
            for (int jc = 0; jc < 4; ++jc) {
                floatx4 v = sacc[hh][jc] * SCALE;
                unsigned int pu = puf[jc];
                if (pu) {
                    if (pu & 0x000000FFu) v[0] = -1.0e9f;
                    if (pu & 0x0000FF00u) v[1] = -1.0e9f;
                    if (pu & 0x00FF0000u) v[2] = -1.0e9f;
                    if (pu & 0xFF000000u) v[3] = -1.0e9f;
                }
                sacc[hh][jc] = v;
                mx = fmaxf(mx, fmaxf(fmaxf(v[0], v[1]), fmaxf(v[2], v[3])));
            }
            mx = fmaxf(mx, __shfl_xor(mx, 16, 64));
            mx = fmaxf(mx, __shfl_xor(mx, 32, 64));
            if (quad == 0) redm[hh][wave][l16] = mx;
        }
        __syncthreads();
#pragma unroll
        for (int hh = 0; hh < 2; ++hh) {
            float m = redm[hh][0][l16];
#pragma unroll
            for (int w = 1; w < 8; ++w) m = fmaxf(m, redm[hh][w][l16]);
            float sum = 0.0f;
#pragma unroll
            for (int jc = 0; jc < 4; ++jc) {
                floatx4 v = sacc[hh][jc];
                v[0] = __expf(v[0] - m); v[1] = __expf(v[1] - m);
                v[2] = __expf(v[2] - m); v[3] = __expf(v[3] - m);
                sacc[hh][jc] = v;
                sum += v[0] + v[1] + v[2] + v[3];
            }
            sum += __shfl_xor(sum, 16, 64);
            sum += __shfl_xor(sum, 32, 64);
            if (quad == 0) reds[hh][wave][l16] = sum;
        }
        __syncthreads();
#pragma unroll
        for (int hh = 0; hh < 2; ++hh) {
            float sum = 0.0f;
#pragma unroll
            for (int w = 0; w < 8; ++w) sum += reds[hh][w][l16];
            float inv = 1.0f / sum;
            unsigned short* prow = P + ((size_t)(b * Hn + h0 + hh) * Tn + i) * Tn;
#pragma unroll
            for (int jc = 0; jc < 4; ++jc) {
                floatx4 v = sacc[hh][jc];
                ushort4 o;
                o.x = f2b(v[0] * inv); o.y = f2b(v[1] * inv);
                o.z = f2b(v[2] * inv); o.w = f2b(v[3] * inv);
                *(ushort4*)(prow + wave * 64 + jc * 16 + quad * 4) = o;
            }
        }
    }
}

// ---------------------------------------------------------------------------
// Fused qk^T + scale + softmax for CROSS-ATTENTION (no em, no pad).
// R1 structure: 4 waves, 16 rows i of one (b,h); wave owns 128 j.
__global__ __launch_bounds__(256) void relsoft_nc(
    const unsigned short* __restrict__ qB,   // (B,H,T,HD) bf16
    const unsigned short* __restrict__ kB,   // (B,H,S,HD) bf16
    unsigned short* __restrict__ P) {        // (B,H,T,S) bf16
    int id = blockIdx.x;
    int c = id & 7, h = (id >> 3) & 7, g = id >> 6;
    int u = g * 8 + c;                 // 0..255
    int b = u >> 5, it = u & 31;
    int bh = b * Hn + h;
    int wave = threadIdx.x >> 6, lane = threadIdx.x & 63;
    int l16 = lane & 15, quad = lane >> 4;
    int i = it * 16 + l16;
    const int JC = Sn / 64;            // 8

    __shared__ float redm[4][16];
    __shared__ float reds[4][16];

    const unsigned short* kp0 = kB + (size_t)bh * Sn * HDn + (size_t)l16 * HDn + quad * 8;
    short8 kf[JC][2];
#pragma unroll
    for (int jc = 0; jc < JC; ++jc) {
        const unsigned short* kp = kp0 + (size_t)(wave * JC + jc) * 16 * HDn;
        kf[jc][0] = *(const short8*)(kp);
        kf[jc][1] = *(const short8*)(kp + 32);
    }
    const unsigned short* ub = qB + (size_t)bh * Tn * HDn + (size_t)i * HDn + quad * 8;
    short8 u0 = *(const short8*)(ub);
    short8 u1 = *(const short8*)(ub + 32);

    floatx4 sacc[JC];
    float mx = -3.0e38f;
#pragma unroll
    for (int jc = 0; jc < JC; ++jc) {
        floatx4 gacc = {0, 0, 0, 0};
        gacc = __builtin_amdgcn_mfma_f32_16x16x32_bf16(kf[jc][0], u0, gacc, 0, 0, 0);
        gacc = __builtin_amdgcn_mfma_f32_16x16x32_bf16(kf[jc][1], u1, gacc, 0, 0, 0);
        floatx4 v = gacc * SCALE;
        sacc[jc] = v;
        mx = fmaxf(mx, fmaxf(fmaxf(v[0], v[1]), fmaxf(v[2], v[3])));
    }
    mx = fmaxf(mx, __shfl_xor(mx, 16, 64));
    mx = fmaxf(mx, __shfl_xor(mx, 32, 64));
    if (quad == 0) redm[wave][l16] = mx;
    __syncthreads();
    mx = fmaxf(fmaxf(redm[0][l16], redm[1][l16]), fmaxf(redm[2][l16], redm[3][l16]));

    float sum = 0.0f;
#pragma unroll
    for (int jc = 0; jc < JC; ++jc) {
        floatx4 v = sacc[jc];
        v[0] = __expf(v[0] - mx); v[1] = __expf(v[1] - mx);
        v[2] = __expf(v[2] - mx); v[3] = __expf(v[3] - mx);
        sacc[jc] = v;
        sum += v[0] + v[1] + v[2] + v[3];
    }
    sum += __shfl_xor(sum, 16, 64);
    sum += __shfl_xor(sum, 32, 64);
    if (quad == 0) reds[wave][l16] = sum;
    __syncthreads();
    sum = (reds[0][l16] + reds[1][l16]) + (reds[2][l16] + reds[3][l16]);
    float inv = 1.0f / sum;

    unsigned short* prow = P + (size_t)bh * Tn * Sn + (size_t)i * Sn;
#pragma unroll
    for (int jc = 0; jc < JC; ++jc) {
        int jt = wave * JC + jc;
        floatx4 v = sacc[jc];
        ushort4 o;
        o.x = f2b(v[0] * inv); o.y = f2b(v[1] * inv);
        o.z = f2b(v[2] * inv); o.w = f2b(v[3] * inv);
        *(ushort4*)(prow + jt * 16 + quad * 4) = o;
    }
}

// ---------------------------------------------------------------------------
// LayerNorm over D=512: out = (a[row] + b2[row] - mean)/sqrt(var+eps)*s + bb
__global__ __launch_bounds__(256) void ln_kernel(
    const float* __restrict__ a, int a_trans, const float* __restrict__ b2,
    const float* __restrict__ s, const float* __restrict__ bb,
    float* __restrict__ outF, int out_trans, unsigned short* __restrict__ outB) {
    int row = blockIdx.x;            // b*Tn + t
    int b = row >> 9, t = row & (Tn - 1);
    int tid = threadIdx.x;
    size_t ia = a_trans ? ((size_t)(t * Bn + b)) * Dn : (size_t)row * Dn;
    size_t ir = (size_t)row * Dn;
    float x0 = a[ia + tid];
    float x1 = a[ia + tid + 256];
    if (b2) { x0 += b2[ir + tid]; x1 += b2[ir + tid + 256]; }
    float s1 = x0 + x1, s2 = x0 * x0 + x1 * x1;
    for (int off = 32; off; off >>= 1) {
        s1 += __shfl_xor(s1, off, 64);
        s2 += __shfl_xor(s2, off, 64);
    }
    __shared__ float red[2][4];
    int wave = tid >> 6, lane = tid & 63;
    if (lane == 0) { red[0][wave] = s1; red[1][wave] = s2; }
    __syncthreads();
    float ts1 = red[0][0] + red[0][1] + red[0][2] + red[0][3];
    float ts2 = red[1][0] + red[1][1] + red[1][2] + red[1][3];
    float mean = ts1 * (1.0f / Dn);
    float var = ts2 * (1.0f / Dn) - mean * mean;
    float rs = rsqrtf(var + 1e-5f);
    float y0 = (x0 - mean) * rs * s[tid] + bb[tid];
    float y1 = (x1 - mean) * rs * s[tid + 256] + bb[tid + 256];
    size_t io = out_trans ? ((size_t)(t * Bn + b)) * Dn : ir;
    if (outF) { outF[io + tid] = y0; outF[io + tid + 256] = y1; }
    if (outB) { outB[ir + tid] = f2b(y0); outB[ir + tid + 256] = f2b(y1); }
}

// ---------------------------------------------------------------------------
extern "C" void kernel_launch(void* const* d_in, const int* in_sizes, int n_in,
                              void* d_out, int out_size, void* d_ws, size_t ws_size,
                              hipStream_t stream) {
    const float* tgt      = (const float*)d_in[0];
    const float* em       = (const float*)d_in[1];
    const unsigned char* pad = (const unsigned char*)d_in[2];
    const float* memr     = (const float*)d_in[3];
    const float* sa_q_w   = (const float*)d_in[4];
    const float* sa_q_b   = (const float*)d_in[5];
    const float* sa_k_w   = (const float*)d_in[6];
    const float* sa_k_b   = (const float*)d_in[7];
    const float* sa_v_w   = (const float*)d_in[8];
    const float* sa_v_b   = (const float*)d_in[9];
    const float* sa_rel   = (const float*)d_in[10];
    const float* sa_out_w = (const float*)d_in[11];
    const float* sa_out_b = (const float*)d_in[12];
    const float* ca_in_w  = (const float*)d_in[13];
    const float* ca_in_b  = (const float*)d_in[14];
    const float* ca_out_w = (const float*)d_in[15];
    const float* ca_out_b = (const float*)d_in[16];
    const float* lin1_w   = (const float*)d_in[17];
    const float* lin1_b   = (const float*)d_in[18];
    const float* lin2_w   = (const float*)d_in[19];
    const float* lin2_b   = (const float*)d_in[20];
    const float* ln1_s    = (const float*)d_in[21];
    const float* ln1_b    = (const float*)d_in[22];
    const float* ln2_s    = (const float*)d_in[23];
    const float* ln2_b    = (const float*)d_in[24];
    const float* ln3_s    = (const float*)d_in[25];
    const float* ln3_b    = (const float*)d_in[26];

    const size_t BT = (size_t)Bn * Tn;   // 4096
    const size_t Q  = 1 << 18;           // 256K elems

    // ---- workspace carve-out ----
    char* ws = (char*)d_ws;
    size_t off = 0;
    auto alloc = [&](size_t bytes) -> char* {
        char* p = ws + off;
        off += (bytes + 255) & ~(size_t)255;
        return p;
    };
    unsigned short* xb   = (unsigned short*)alloc(BT * Dn * 2);
    unsigned short* mb   = (unsigned short*)alloc(BT * Dn * 2);
    unsigned short* wall = (unsigned short*)alloc((16 * Q + Ln * HDn * HDn) * 2);
    float*          bqkv = (float*)alloc(3 * Dn * 4);
    unsigned short* qb   = (unsigned short*)alloc(BT * Dn * 2);          // (B,H,T,HD)
    unsigned short* kb   = (unsigned short*)alloc(BT * Dn * 2);          // (B,H,T,HD)
    unsigned short* vtb  = (unsigned short*)alloc(BT * Dn * 2);          // (B,H,HD,T)
    unsigned short* ur   = (unsigned short*)alloc((size_t)Bn * Hn * Ln * Tn * HDn * 2);
    unsigned short* pb   = (unsigned short*)alloc((size_t)Bn * Hn * Tn * Tn * 2); // 32MB probs
    unsigned short* ob   = (unsigned short*)alloc(BT * Dn * 2);
    float*          t2f  = (float*)alloc(BT * Dn * 4);
    float*          x1f  = (float*)alloc(BT * Dn * 4);
    unsigned short* x1b  = (unsigned short*)alloc(BT * Dn * 2);
    float*          x2f  = (float*)alloc(BT * Dn * 4);
    unsigned short* x2b  = (unsigned short*)alloc(BT * Dn * 2);
    unsigned short* hid  = (unsigned short*)alloc(BT * Fn * 2);
    (void)ws_size; (void)in_sizes; (void)n_in; (void)out_size;

    // arena views
    unsigned short* wqkv = wall;
    unsigned short* wsao = wall + 3 * Q;
    unsigned short* wcain = wall + 4 * Q;
    unsigned short* wcao = wall + 7 * Q;
    unsigned short* wlin1 = wall + 8 * Q;
    unsigned short* wlin2 = wall + 12 * Q;
    unsigned short* wrel = wall + 16 * Q;

    auto gemm = [&](const unsigned short* A, const unsigned short* W, const float* bias,
                    void* C, void* C2, void* C3, int M, int N, int K, int lda, int ldw, int ldc,
                    long sA1, long sA2, long sW1, long sW2, long sC1, long sC2,
                    int zdiv, int batches, float alpha, int mode, int relu, int Tp) {
        dim3 g(N / 64, M / 64, batches);
        gemm_bf16<<<g, 256, 0, stream>>>(A, W, bias, C, C2, C3, M, N, K, lda, ldw, ldc,
                                         sA1, sA2, sW1, sW2, sC1, sC2, zdiv,
                                         alpha, mode, relu, Tp);
    };
    // 128x128 tile
    auto gemmBig = [&](const unsigned short* A, const unsigned short* W, const float* bias,
                       void* C, void* C2, void* C3, int M, int N, int K,
                       int lda, int ldw, int ldc, float alpha, int mode, int relu, int Tp) {
        dim3 g(N / 128, M / 128, 1);
        gemmT_bf16<4, 4><<<g, 256, 0, stream>>>(A, W, bias, C, C2, C3, K, lda, ldw, ldc,
                                                alpha, mode, relu, Tp);
    };
    // 128x64 tile (N=512 cases -> 256 blocks = 1/CU)
    auto gemmMed = [&](const unsigned short* A, const unsigned short* W, const float* bias,
                       void* C, void* C2, void* C3, int M, int N, int K,
                       int lda, int ldw, int ldc, float alpha, int mode, int relu, int Tp) {
        dim3 g(N / 64, M / 128, 1);
        gemmT_bf16<4, 2><<<g, 256, 0, stream>>>(A, W, bias, C, C2, C3, K, lda, ldw, ldc,
                                                alpha, mode, relu, Tp);
    };

    // ---- prep ----
    to_rows_bf16<<<dim3((BT * Dn + 255) / 256), 256, 0, stream>>>(tgt, xb, Tn);
    to_rows_bf16<<<dim3((BT * Dn + 255) / 256), 256, 0, stream>>>(memr, mb, Sn);
    conv_all<<<dim3((16 * Q + Ln * HDn * HDn + 3 * Dn + 255) / 256), 256, 0, stream>>>(
        sa_q_w, sa_k_w, sa_v_w, sa_out_w, ca_in_w, ca_out_w, lin1_w, lin2_w, sa_rel,
        sa_q_b, sa_k_b, sa_v_b, wall, bqkv);

    // ---- self-attention ----
    // fused q,k,v: (B,H,T,HD) x2 + v as (B,H,HD,T)
    gemmBig(xb, wqkv, bqkv, qb, kb, vtb, (int)BT, 3 * Dn, Dn, Dn, Dn, 0, 1.0f, 4, 0, Tn);
    // uR[b,h,l] = q[b,h] @ R_l^T  (batched over B*H*L)
    gemm(qb, wrel, nullptr, ur, nullptr, nullptr, Tn, HDn, HDn, HDn, HDn, HDn,
         (long)Tn * HDn, 0, 0, (long)HDn * HDn, (long)Ln * Tn * HDn, (long)Tn * HDn,
         Ln, Bn * Hn * Ln, 1.0f, 1, 0, 0);
    // fused rel-scores + em + scale + pad + softmax -> bf16 P
    relsoft_em<<<dim3(256), 512, 0, stream>>>(ur, kb, em, pad, pb);
    // O = P @ V
    gemm(pb, vtb, nullptr, ob, nullptr, nullptr, Tn, HDn, Tn, Tn, Tn, Dn,
         (long)Hn * Tn * Tn, (long)Tn * Tn, (long)Hn * HDn * Tn, (long)HDn * Tn,
         (long)Tn * Dn, 64, Hn, Bn * Hn, 1.0f, 1, 0, 0);
    gemmMed(ob, wsao, sa_out_b, t2f, nullptr, nullptr, (int)BT, Dn, Dn, Dn, Dn, Dn,
            1.0f, 0, 0, 0);
    ln_kernel<<<dim3((int)BT), 256, 0, stream>>>(tgt, 1, t2f, ln1_s, ln1_b, x1f, 0, x1b);

    // ---- cross-attention ----
    gemmMed(x1b, wcain, ca_in_b, qb, nullptr, nullptr, (int)BT, Dn, Dn, Dn, Dn, 0,
            1.0f, 2, 0, Tn);
    // fused k,v from memory
    gemmBig(mb, wcain + (size_t)Dn * Dn, ca_in_b + Dn, kb, vtb, nullptr, (int)BT, 2 * Dn, Dn,
            Dn, Dn, 0, 1.0f, 5, 0, Sn);
    // fused qk^T + scale + softmax -> bf16 P
    relsoft_nc<<<dim3(2048), 256, 0, stream>>>(qb, kb, pb);
    gemm(pb, vtb, nullptr, ob, nullptr, nullptr, Tn, HDn, Sn, Sn, Sn, Dn,
         (long)Hn * Tn * Sn, (long)Tn * Sn, (long)Hn * HDn * Sn, (long)HDn * Sn,
         (long)Tn * Dn, 64, Hn, Bn * Hn, 1.0f, 1, 0, 0);
    gemmMed(ob, wcao, ca_out_b, t2f, nullptr, nullptr, (int)BT, Dn, Dn, Dn, Dn, Dn,
            1.0f, 0, 0, 0);
    ln_kernel<<<dim3((int)BT), 256, 0, stream>>>(x1f, 0, t2f, ln2_s, ln2_b, x2f, 0, x2b);

    // ---- FFN ----
    gemmBig(x2b, wlin1, lin1_b, hid, nullptr, nullptr, (int)BT, Fn, Dn, Dn, Dn, Fn,
            1.0f, 1, 1, 0);
    gemmMed(hid, wlin2, lin2_b, t2f, nullptr, nullptr, (int)BT, Dn, Fn, Fn, Fn, Dn,
            1.0f, 0, 0, 0);
    ln_kernel<<<dim3((int)BT), 256, 0, stream>>>(x2f, 0, t2f, ln3_s, ln3_b, (float*)d_out, 1, nullptr);
}

// Round 5
// 615.625 us; speedup vs baseline: 1.3363x; 1.0423x over previous
//
#include <hip/hip_runtime.h>

// Problem constants
#define Tn 512
#define Sn 512
#define Bn 8
#define Dn 512
#define Hn 8
#define HDn 64
#define Ln 8
#define Fn 2048
#define SCALE 0.125f

typedef short short8 __attribute__((ext_vector_type(8)));
typedef float floatx4 __attribute__((ext_vector_type(4)));

__device__ __forceinline__ unsigned short f2b(float f) {
    unsigned int u = __float_as_uint(f);
    u += 0x7FFFu + ((u >> 16) & 1u);   // round-to-nearest-even
    return (unsigned short)(u >> 16);
}

// ---------------------------------------------------------------------------
// Prep: (T,B,D) f32 -> (B*T, D) bf16 rows
__global__ __launch_bounds__(256) void to_rows_bf16(const float* __restrict__ in,
                                                    unsigned short* __restrict__ out, int T_) {
    size_t n = (size_t)blockIdx.x * 256 + threadIdx.x;
    size_t total = (size_t)T_ * Bn * Dn;
    if (n >= total) return;
    int d = (int)(n & (Dn - 1));
    size_t rt = n >> 9;              // Dn = 512
    int t = (int)(rt % T_);
    int b = (int)(rt / T_);
    out[n] = f2b(in[((size_t)t * Bn + b) * Dn + d]);
}

// ---------------------------------------------------------------------------
// One-shot weight conversion into a packed bf16 arena + concatenated qkv bias.
// Arena layout (units of 256K = 1<<18 elems): [0..3):qkv  [3]:sao  [4..7):cain
// [7]:cao  [8..12):lin1  [12..16):lin2  [16]:rel(32K)
__global__ __launch_bounds__(256) void conv_all(
    const float* __restrict__ qw, const float* __restrict__ kw, const float* __restrict__ vw,
    const float* __restrict__ sow, const float* __restrict__ ciw, const float* __restrict__ cow,
    const float* __restrict__ l1w, const float* __restrict__ l2w, const float* __restrict__ rel,
    const float* __restrict__ qbias, const float* __restrict__ kbias, const float* __restrict__ vbias,
    unsigned short* __restrict__ wall, float* __restrict__ bqkv) {
    const int Q = 1 << 18;
    const int total = 16 * Q + Ln * HDn * HDn;   // 4227072
    int i = blockIdx.x * 256 + threadIdx.x;
    if (i < total) {
        int seg = i >> 18, r = i & (Q - 1);
        float v;
        if (seg < 3)       v = (seg == 0 ? qw : (seg == 1 ? kw : vw))[r];
        else if (seg == 3) v = sow[r];
        else if (seg < 7)  v = ciw[(size_t)(seg - 4) * Q + r];
        else if (seg == 7) v = cow[r];
        else if (seg < 12) v = l1w[(size_t)(seg - 8) * Q + r];
        else if (seg < 16) v = l2w[(size_t)(seg - 12) * Q + r];
        else               v = rel[r];
        wall[i] = f2b(v);
    }
    int j = i - total;
    if (j >= 0 && j < 3 * Dn)
        bqkv[j] = (j < Dn ? qbias[j] : (j < 2 * Dn ? kbias[j - Dn] : vbias[j - 2 * Dn]));
}

// ---------------------------------------------------------------------------
// Shared epilogue: scatter one 16x16 C tile per (mt,nt) per mode.
// mode 0: f32 row-major   1: bf16 row-major   2: bf16 heads (B,H,T,HD)
// mode 3: bf16 headsT (B,H,HD,T)
// mode 4: fused qkv split: gn<512->Cv heads, <1024->Cv2 heads, else Cv3 headsT
// mode 5: fused kv  split: gn<512->Cv heads, else Cv2 headsT
__device__ __forceinline__ void c_scatter(
    floatx4 v, int gm, int gn, size_t coff, int ldc, float alpha, float bb,
    int mode, int relu, int Tp, void* Cv, void* Cv2, void* Cv3) {
    for (int r = 0; r < 4; ++r) {
        float val = v[r] * alpha + bb;
        if (relu) val = fmaxf(val, 0.0f);
        int m = gm + r;
        if (mode == 0) {
            ((float*)Cv)[coff + (size_t)m * ldc + gn] = val;
        } else if (mode == 1) {
            ((unsigned short*)Cv)[coff + (size_t)m * ldc + gn] = f2b(val);
        } else if (mode == 2) {
            int bq = m / Tp, t = m - bq * Tp;
            ((unsigned short*)Cv)[(((size_t)(bq * Hn + (gn >> 6)) * Tp + t) << 6) + (gn & 63)] = f2b(val);
        } else if (mode == 3) {
            int bq = m / Tp, t = m - bq * Tp;
            ((unsigned short*)Cv)[((size_t)(bq * Hn + (gn >> 6)) * 64 + (gn & 63)) * Tp + t] = f2b(val);
        } else if (mode == 4) {
            int sel = gn >> 9, g2 = gn & 511;
            int bq = m / Tp, t = m - bq * Tp;
            int hh = g2 >> 6, dd = g2 & 63;
            if (sel == 0)
                ((unsigned short*)Cv)[(((size_t)(bq * Hn + hh) * Tp + t) << 6) + dd] = f2b(val);
            else if (sel == 1)
                ((unsigned short*)Cv2)[(((size_t)(bq * Hn + hh) * Tp + t) << 6) + dd] = f2b(val);
            else
                ((unsigned short*)Cv3)[((size_t)(bq * Hn + hh) * 64 + dd) * Tp + t] = f2b(val);
        } else { // mode 5
            int sel = gn >> 9, g2 = gn & 511;
            int bq = m / Tp, t = m - bq * Tp;
            int hh = g2 >> 6, dd = g2 & 63;
            if (sel == 0)
                ((unsigned short*)Cv)[(((size_t)(bq * Hn + hh) * Tp + t) << 6) + dd] = f2b(val);
            else
                ((unsigned short*)Cv2)[((size_t)(bq * Hn + hh) * 64 + dd) * Tp + t] = f2b(val);
        }
    }
}

// ---------------------------------------------------------------------------
// Batched bf16 MFMA GEMM, 64x64 block tile (heavily-batched attn GEMMs).
__global__ __launch_bounds__(256) void gemm_bf16(
    const unsigned short* __restrict__ A, const unsigned short* __restrict__ W,
    const float* __restrict__ bias, void* __restrict__ Cv, void* __restrict__ Cv2,
    void* __restrict__ Cv3,
    int M, int N, int K, int lda, int ldw, int ldc,
    long sA1, long sA2, long sW1, long sW2, long sC1, long sC2, int zdiv,
    float alpha, int mode, int relu, int Tp) {
    int z = blockIdx.z;
    int z1 = z / zdiv, z2 = z - z1 * zdiv;
    const unsigned short* Ab = A + (size_t)z1 * sA1 + (size_t)z2 * sA2;
    const unsigned short* Wb = W + (size_t)z1 * sW1 + (size_t)z2 * sW2;
    size_t coff = (size_t)z1 * sC1 + (size_t)z2 * sC2;
    int tid = threadIdx.x;
    int lane = tid & 63, wave = tid >> 6;
    int wm = wave & 1, wn = wave >> 1;
    int l16 = lane & 15, quad = lane >> 4;
    int m0 = blockIdx.y * 64 + wm * 32;
    int n0 = blockIdx.x * 64 + wn * 32;

    floatx4 acc00 = {0,0,0,0}, acc01 = {0,0,0,0}, acc10 = {0,0,0,0}, acc11 = {0,0,0,0};
    const unsigned short* a0p = Ab + (size_t)(m0 + l16) * lda + quad * 8;
    const unsigned short* a1p = a0p + (size_t)16 * lda;
    const unsigned short* b0p = Wb + (size_t)(n0 + l16) * ldw + quad * 8;
    const unsigned short* b1p = b0p + (size_t)16 * ldw;

#pragma unroll 2
    for (int kk = 0; kk < K; kk += 32) {
        short8 a0 = *(const short8*)(a0p + kk);
        short8 a1 = *(const short8*)(a1p + kk);
        short8 b0 = *(const short8*)(b0p + kk);
        short8 b1 = *(const short8*)(b1p + kk);
        acc00 = __builtin_amdgcn_mfma_f32_16x16x32_bf16(a0, b0, acc00, 0, 0, 0);
        acc01 = __builtin_amdgcn_mfma_f32_16x16x32_bf16(a0, b1, acc01, 0, 0, 0);
        acc10 = __builtin_amdgcn_mfma_f32_16x16x32_bf16(a1, b0, acc10, 0, 0, 0);
        acc11 = __builtin_amdgcn_mfma_f32_16x16x32_bf16(a1, b1, acc11, 0, 0, 0);
    }
    floatx4 accs[2][2] = {{acc00, acc01}, {acc10, acc11}};
    for (int mt = 0; mt < 2; ++mt)
        for (int nt = 0; nt < 2; ++nt) {
            int gn = n0 + nt * 16 + l16;
            float bb = bias ? bias[gn] : 0.0f;
            c_scatter(accs[mt][nt], m0 + mt * 16 + quad * 4, gn, coff, ldc,
                      alpha, bb, mode, relu, Tp, Cv, Cv2, Cv3);
        }
}

// ---------------------------------------------------------------------------
// bf16 MFMA GEMM, templated tile: block = 2x2 waves, each wave MT*16 x NT*16.
template <int MT, int NT>
__global__ __launch_bounds__(256) void gemmT_bf16(
    const unsigned short* __restrict__ A, const unsigned short* __restrict__ W,
    const float* __restrict__ bias, void* __restrict__ Cv, void* __restrict__ Cv2,
    void* __restrict__ Cv3,
    int K, int lda, int ldw, int ldc,
    float alpha, int mode, int relu, int Tp) {
    int tid = threadIdx.x;
    int lane = tid & 63, wave = tid >> 6;
    int wm = wave & 1, wn = wave >> 1;
    int l16 = lane & 15, quad = lane >> 4;
    int m0 = blockIdx.y * (MT * 32) + wm * (MT * 16);
    int n0 = blockIdx.x * (NT * 32) + wn * (NT * 16);

    floatx4 acc[MT][NT] = {};
    const unsigned short* ap = A + (size_t)(m0 + l16) * lda + quad * 8;
    const unsigned short* bp = W + (size_t)(n0 + l16) * ldw + quad * 8;

    for (int kk = 0; kk < K; kk += 32) {
        short8 a[MT], b[NT];
#pragma unroll
        for (int mt = 0; mt < MT; ++mt)
            a[mt] = *(const short8*)(ap + (size_t)mt * 16 * lda + kk);
#pragma unroll
        for (int nt = 0; nt < NT; ++nt)
            b[nt] = *(const short8*)(bp + (size_t)nt * 16 * ldw + kk);
#pragma unroll
        for (int mt = 0; mt < MT; ++mt)
#pragma unroll
            for (int nt = 0; nt < NT; ++nt)
                acc[mt][nt] = __builtin_amdgcn_mfma_f32_16x16x32_bf16(a[mt], b[nt], acc[mt][nt], 0, 0, 0);
    }
    for (int mt = 0; mt < MT; ++mt)
        for (int nt = 0; nt < NT; ++nt) {
            int gn = n0 + nt * 16 + l16;
            float bb = bias ? bias[gn] : 0.0f;
            c_scatter(acc[mt][nt], m0 + mt * 16 + quad * 4, gn, 0, ldc,
                      alpha, bb, mode, relu, Tp, Cv, Cv2, Cv3);
        }
}

// ---------------------------------------------------------------------------
// R12: fused rel-scores + em + scale + pad + softmax (self-attention).
// Grid 1024 = (b, it, hp): one block = one 16-row i-tile x one HEAD-PAIR x
// full j=512. 512 threads = 8 waves; wave w owns j in [w*64, w*64+64).
// The 4 hp-siblings of each (b,it) are swizzled to the SAME XCD and run
// CONCURRENTLY -> their em reads merge in L2/MSHR (R1-proven: FETCH=66MB),
// so em costs ~1x HBM despite 4 sibling readers.
//
// Steady loop (l = 0..7) is barrier-FREE with a depth-3 counted-vmcnt
// pipeline: 3 em buffers, wave-PRIVATE 4KB bands (stage band == read band),
// the only in-loop VMEM is the 4 stage loads/wave/step -> counts are exact:
//   wait vmcnt(8): stage(l) done (issued 3 phases earlier), stage(l+1),(l+2)
//   in flight.  Tail: vmcnt(4) at l=6, vmcnt(0) at l=7.
// u fragments: the pair's entire uR slice (32KB) staged to LDS once in the
// prologue (raw s_barrier; per-wave vmcnt(12) proves each wave's part done),
// then read via swizzled ds_read_b128 -> no global u loads in the stream.
// XOR-swizzles on both em and u LDS make all reads ~2-way (free).
// VGPR ~ kf64 + sacc32 + emr16 + u16 + misc ~ 160 (no spill; watch WRITE).
__global__ __launch_bounds__(512, 2) void relsoft_em(
    const unsigned short* __restrict__ uR,   // (B,H,L,T,HD) bf16
    const unsigned short* __restrict__ kB,   // (B,H,T,HD) bf16
    const float* __restrict__ em,            // (B,L,T,T) f32
    const unsigned char* __restrict__ pad,   // (B,T,T)
    unsigned short* __restrict__ P) {        // (B,H,T,T) bf16
    int id = blockIdx.x;
    // sibling-concurrent XCD mapping: ids {x, x+8, x+16, x+24} share (b,it)
    // and differ in hp; default round-robin puts them on the SAME XCD slot.
    int r5 = id & 31, q5 = id >> 5;
    int hp = r5 >> 3;                  // 0..3
    int uu = q5 * 8 + (r5 & 7);        // 0..255
    int b = uu >> 5, it = uu & 31;
    int h0 = hp * 2;
    int tid = threadIdx.x;
    int wave = tid >> 6, lane = tid & 63;
    int l16 = lane & 15, quad = lane >> 4;
    int i = it * 16 + l16;

    // LDS: em 3 bufs x 8 waves x 4KB = 96KB; u 256 rows x 128B = 32KB; red 2KB
    __shared__ float emS[3 * 8 * 1024];
    __shared__ float uS[256 * 32];
    __shared__ float redm[2][8][16];
    __shared__ float reds[2][8][16];

    const float* emBase = em + ((size_t)b * Ln * Tn + (size_t)it * 16) * Tn;

    // Stage em slice sl into buf: wave-private band = 16 rows x 16 granules
    // of 16B (j in [wave*64, wave*64+64)). Slot (r, sc) holds source granule
    // col (sc ^ r) -> read at slot (c ^ r) is bank-conflict-~free.
    auto stageEM = [&](int sl, int buf) {
        const float* rowb = emBase + (size_t)sl * Tn * Tn;
        float* wb = emS + (size_t)(buf * 8 + wave) * 1024;
#pragma unroll
        for (int k = 0; k < 4; ++k) {
            int s = k * 64 + lane;
            int rr = s >> 4, sc = s & 15;
            const float* gp = rowb + (size_t)rr * Tn + (wave * 16 + (sc ^ rr)) * 4;
            __builtin_amdgcn_global_load_lds(
                (const __attribute__((address_space(1))) void*)gp,
                (__attribute__((address_space(3))) void*)(wb + k * 256), 16, 0, 0);
        }
    };

    // ---- prologue phase 1: plain loads (pad + kf), drained before the
    // counted stream starts so in-loop vmcnt counts stay exact.
    unsigned int puf[4];
#pragma unroll
    for (int jc = 0; jc < 4; ++jc)
        puf[jc] = *(const unsigned int*)(pad + ((size_t)b * Tn + i) * Tn +
                                         wave * 64 + jc * 16 + quad * 4);
    short8 kf[2][4][2];
#pragma unroll
    for (int hh = 0; hh < 2; ++hh)
#pragma unroll
        for (int jc = 0; jc < 4; ++jc) {
            const unsigned short* kp = kB + ((size_t)(b * Hn + h0 + hh) * Tn +
                                             wave * 64 + jc * 16 + l16) * HDn + quad * 8;
            kf[hh][jc][0] = *(const short8*)(kp);
            kf[hh][jc][1] = *(const short8*)(kp + 32);
        }
    __builtin_amdgcn_sched_barrier(0);
    asm volatile("s_waitcnt vmcnt(0)");
    __builtin_amdgcn_sched_barrier(0);

    // ---- prologue phase 2: counted stream. u-stage (4 instrs) FIRST, then
    // em stages (3 x 4). Order pinned by sched_barriers.
    // uS row = (hh*Ln + l)*16 + ii; granule slot sc holds source granule
    // (sc ^ (ii&7)).  Wave stages rows [wave*32, wave*32+32).
#pragma unroll
    for (int k = 0; k < 4; ++k) {
        int s = k * 64 + lane;
        int rl = s >> 3, sc = s & 7;
        int row = wave * 32 + rl;
        int hh = row >> 7, rem = row & 127;
        int ll = rem >> 4, ii = rem & 15;
        const unsigned short* gp = uR + (((size_t)(b * Hn + h0 + hh) * Ln + ll) * Tn +
                                         it * 16 + ii) * HDn + (sc ^ (ii & 7)) * 8;
        __builtin_amdgcn_global_load_lds(
            (const __attribute__((address_space(1))) void*)gp,
            (__attribute__((address_space(3))) void*)(uS + (size_t)wave * 1024 + k * 256),
            16, 0, 0);
    }
    __builtin_amdgcn_sched_barrier(0);
    stageEM(0, 0);
    __builtin_amdgcn_sched_barrier(0);
    stageEM(1, 1);
    __builtin_amdgcn_sched_barrier(0);
    stageEM(2, 2);
    __builtin_amdgcn_sched_barrier(0);
    asm volatile("s_waitcnt vmcnt(12)");   // u-stage retired; em 0..2 in flight
    __builtin_amdgcn_sched_barrier(0);
    __builtin_amdgcn_s_barrier();          // raw barrier: uS visible to all waves

    // ---- steady loop: barrier-free, depth-3 counted vmcnt
    floatx4 sacc[2][4] = {};
#pragma clang loop unroll(disable)
    for (int l = 0; l < Ln; ++l) {
        int buf = l % 3;
        if (l < 6)       { asm volatile("s_waitcnt vmcnt(8)"); }
        else if (l == 6) { asm volatile("s_waitcnt vmcnt(4)"); }
        else             { asm volatile("s_waitcnt vmcnt(0)"); }
        __builtin_amdgcn_sched_barrier(0);

        const float* rb = emS + (size_t)(buf * 8 + wave) * 1024;
        floatx4 emr[4];
#pragma unroll
        for (int jc = 0; jc < 4; ++jc) {
            int sc = (jc * 4 + quad) ^ l16;
            emr[jc] = *(const floatx4*)(rb + l16 * 64 + sc * 4);
        }
        const float* u0row = uS + (size_t)((0 * Ln + l) * 16 + l16) * 32;
        const float* u1row = uS + (size_t)((1 * Ln + l) * 16 + l16) * 32;
        int us0 = (quad ^ (l16 & 7)) * 4;
        int us1 = ((quad + 4) ^ (l16 & 7)) * 4;
        short8 u0a = *(const short8*)(u0row + us0);
        short8 u0b = *(const short8*)(u0row + us1);
        short8 u1a = *(const short8*)(u1row + us0);
        short8 u1b = *(const short8*)(u1row + us1);
        asm volatile("s_waitcnt lgkmcnt(0)");
        __builtin_amdgcn_sched_barrier(0);
        if (l + 3 < Ln) stageEM(l + 3, buf);   // into the buffer just freed
        __builtin_amdgcn_sched_barrier(0);

#pragma unroll
        for (int jc = 0; jc < 4; ++jc) {
            floatx4 g0 = {0, 0, 0, 0};
            g0 = __builtin_amdgcn_mfma_f32_16x16x32_bf16(kf[0][jc][0], u0a, g0, 0, 0, 0);
            g0 = __builtin_amdgcn_mfma_f32_16x16x32_bf16(kf[0][jc][1], u0b, g0, 0, 0, 0);
            sacc[0][jc] += emr[jc] * g0;
            floatx4 g1 = {0, 0, 0, 0};
            g1 = __builtin_amdgcn_mfma_f32_16x16x32_bf16(kf[1][jc][0], u1a, g1, 0, 0, 0);
            g1 = __builtin_amdgcn_mfma_f32_16x16x32_bf16(kf[1][jc][1], u1b, g1, 0, 0, 0);
            sacc[1][jc] += emr[jc] * g1;
        }
    }

    // ---- softmax epilogue for the pair ----
#pragma unroll
    for (int hh = 0; hh < 2; ++hh) {
        float mx = -3.0e38f;
#pragma unroll
        for (int jc = 0; jc < 4; ++jc) {
            floatx4 v = sacc[hh][jc] * SCALE;
            unsigned int pu = puf[jc];
            if (pu) {
                if (pu & 0x000000FFu) v[0] = -1.0e9f;
                if (pu & 0x0000FF00u) v[1] = -1.0e9f;
                if (pu & 0x00FF0000u) v[2] = -1.0e9f;
                if (pu & 0xFF000000u) v[3] = -1.0e9f;
            }
            sacc[hh][jc] = v;
            mx = fmaxf(mx, fmaxf(fmaxf(v[0], v[1]), fmaxf(v[2], v[3])));
        }
        mx = fmaxf(mx, __shfl_xor(mx, 16, 64));
        mx = fmaxf(mx, __shfl_xor(mx, 32, 64));
        if (quad == 0) redm[hh][wave][l16] = mx;
    }
    __syncthreads();
#pragma unroll
    for (int hh = 0; hh < 2; ++hh) {
        float m = redm[hh][0][l16];
#pragma unroll
        for (int w = 1; w < 8; ++w) m = fmaxf(m, redm[hh][w][l16]);
        float sum = 0.0f;
#pragma unroll
        for (int jc = 0; jc < 4; ++jc) {
            floatx4 v = sacc[hh][jc];
            v[0] = __expf(v[0] - m); v[1] = __expf(v[1] - m);
            v[2] = __expf(v[2] - m); v[3] = __expf(v[3] - m);
            sacc[hh][jc] = v;
            sum += v[0] + v[1] + v[2] + v[3];
        }
        sum += __shfl_xor(sum, 16, 64);
        sum += __shfl_xor(sum, 32, 64);
        if (quad == 0) reds[hh][wave][l16] = sum;
    }
    __syncthreads();
#pragma unroll
    for (int hh = 0; hh < 2; ++hh) {
        float sum = 0.0f;
#pragma unroll
        for (int w = 0; w < 8; ++w) sum += reds[hh][w][l16];
        float inv = 1.0f / sum;
        unsigned short* prow = P + ((size_t)(b * Hn + h0 + hh) * Tn + i) * Tn;
#pragma unroll
        for (int jc = 0; jc < 4; ++jc) {
            floatx4 v = sacc[hh][jc];
            ushort4 o;
            o.x = f2b(v[0] * inv); o.y = f2b(v[1] * inv);
            o.z = f2b(v[2] * inv); o.w = f2b(v[3] * inv);
            *(ushort4*)(prow + wave * 64 + jc * 16 + quad * 4) = o;
        }
    }
}

// ---------------------------------------------------------------------------
// Fused qk^T + scale + softmax for CROSS-ATTENTION (no em, no pad).
// 4 waves, 16 rows i of one (b,h); wave owns 128 j.
__global__ __launch_bounds__(256) void relsoft_nc(
    const unsigned short* __restrict__ qB,   // (B,H,T,HD) bf16
    const unsigned short* __restrict__ kB,   // (B,H,S,HD) bf16
    unsigned short* __restrict__ P) {        // (B,H,T,S) bf16
    int id = blockIdx.x;
    int c = id & 7, h = (id >> 3) & 7, g = id >> 6;
    int u = g * 8 + c;                 // 0..255
    int b = u >> 5, it = u & 31;
    int bh = b * Hn + h;
    int wave = threadIdx.x >> 6, lane = threadIdx.x & 63;
    int l16 = lane & 15, quad = lane >> 4;
    int i = it * 16 + l16;
    const int JC = Sn / 64;            // 8

    __shared__ float redm[4][16];
    __shared__ float reds[4][16];

    const unsigned short* kp0 = kB + (size_t)bh * Sn * HDn + (size_t)l16 * HDn + quad * 8;
    short8 kf[JC][2];
#pragma unroll
    for (int jc = 0; jc < JC; ++jc) {
        const unsigned short* kp = kp0 + (size_t)(wave * JC + jc) * 16 * HDn;
        kf[jc][0] = *(const short8*)(kp);
        kf[jc][1] = *(const short8*)(kp + 32);
    }
    const unsigned short* ub = qB + (size_t)bh * Tn * HDn + (size_t)i * HDn + quad * 8;
    short8 u0 = *(const short8*)(ub);
    short8 u1 = *(const short8*)(ub + 32);

    floatx4 sacc[JC];
    float mx = -3.0e38f;
#pragma unroll
    for (int jc = 0; jc < JC; ++jc) {
        floatx4 gacc = {0, 0, 0, 0};
        gacc = __builtin_amdgcn_mfma_f32_16x16x32_bf16(kf[jc][0], u0, gacc, 0, 0, 0);
        gacc = __builtin_amdgcn_mfma_f32_16x16x32_bf16(kf[jc][1], u1, gacc, 0, 0, 0);
        floatx4 v = gacc * SCALE;
        sacc[jc] = v;
        mx = fmaxf(mx, fmaxf(fmaxf(v[0], v[1]), fmaxf(v[2], v[3])));
    }
    mx = fmaxf(mx, __shfl_xor(mx, 16, 64));
    mx = fmaxf(mx, __shfl_xor(mx, 32, 64));
    if (quad == 0) redm[wave][l16] = mx;
    __syncthreads();
    mx = fmaxf(fmaxf(redm[0][l16], redm[1][l16]), fmaxf(redm[2][l16], redm[3][l16]));

    float sum = 0.0f;
#pragma unroll
    for (int jc = 0; jc < JC; ++jc) {
        floatx4 v = sacc[jc];
        v[0] = __expf(v[0] - mx); v[1] = __expf(v[1] - mx);
        v[2] = __expf(v[2] - mx); v[3] = __expf(v[3] - mx);
        sacc[jc] = v;
        sum += v[0] + v[1] + v[2] + v[3];
    }
    sum += __shfl_xor(sum, 16, 64);
    sum += __shfl_xor(sum, 32, 64);
    if (quad == 0) reds[wave][l16] = sum;
    __syncthreads();
    sum = (reds[0][l16] + reds[1][l16]) + (reds[2][l16] + reds[3][l16]);
    float inv = 1.0f / sum;

    unsigned short* prow = P + (size_t)bh * Tn * Sn + (size_t)i * Sn;
#pragma unroll
    for (int jc = 0; jc < JC; ++jc) {
        int jt = wave * JC + jc;
        floatx4 v = sacc[jc];
        ushort4 o;
        o.x = f2b(v[0] * inv); o.y = f2b(v[1] * inv);
        o.z = f2b(v[2] * inv); o.w = f2b(v[3] * inv);
        *(ushort4*)(prow + jt * 16 + quad * 4) = o;
    }
}

// ---------------------------------------------------------------------------
// LayerNorm over D=512: out = (a[row] + b2[row] - mean)/sqrt(var+eps)*s + bb
__global__ __launch_bounds__(256) void ln_kernel(
    const float* __restrict__ a, int a_trans, const float* __restrict__ b2,
    const float* __restrict__ s, const float* __restrict__ bb,
    float* __restrict__ outF, int out_trans, unsigned short* __restrict__ outB) {
    int row = blockIdx.x;            // b*Tn + t
    int b = row >> 9, t = row & (Tn - 1);
    int tid = threadIdx.x;
    size_t ia = a_trans ? ((size_t)(t * Bn + b)) * Dn : (size_t)row * Dn;
    size_t ir = (size_t)row * Dn;
    float x0 = a[ia + tid];
    float x1 = a[ia + tid + 256];
    if (b2) { x0 += b2[ir + tid]; x1 += b2[ir + tid + 256]; }
    float s1 = x0 + x1, s2 = x0 * x0 + x1 * x1;
    for (int off = 32; off; off >>= 1) {
        s1 += __shfl_xor(s1, off, 64);
        s2 += __shfl_xor(s2, off, 64);
    }
    __shared__ float red[2][4];
    int wave = tid >> 6, lane = tid & 63;
    if (lane == 0) { red[0][wave] = s1; red[1][wave] = s2; }
    __syncthreads();
    float ts1 = red[0][0] + red[0][1] + red[0][2] + red[0][3];
    float ts2 = red[1][0] + red[1][1] + red[1][2] + red[1][3];
    float mean = ts1 * (1.0f / Dn);
    float var = ts2 * (1.0f / Dn) - mean * mean;
    float rs = rsqrtf(var + 1e-5f);
    float y0 = (x0 - mean) * rs * s[tid] + bb[tid];
    float y1 = (x1 - mean) * rs * s[tid + 256] + bb[tid + 256];
    size_t io = out_trans ? ((size_t)(t * Bn + b)) * Dn : ir;
    if (outF) { outF[io + tid] = y0; outF[io + tid + 256] = y1; }
    if (outB) { outB[ir + tid] = f2b(y0); outB[ir + tid + 256] = f2b(y1); }
}

// ---------------------------------------------------------------------------
extern "C" void kernel_launch(void* const* d_in, const int* in_sizes, int n_in,
                              void* d_out, int out_size, void* d_ws, size_t ws_size,
                              hipStream_t stream) {
    const float* tgt      = (const float*)d_in[0];
    const float* em       = (const float*)d_in[1];
    const unsigned char* pad = (const unsigned char*)d_in[2];
    const float* memr     = (const float*)d_in[3];
    const float* sa_q_w   = (const float*)d_in[4];
    const float* sa_q_b   = (const float*)d_in[5];
    const float* sa_k_w   = (const float*)d_in[6];
    const float* sa_k_b   = (const float*)d_in[7];
    const float* sa_v_w   = (const float*)d_in[8];
    const float* sa_v_b   = (const float*)d_in[9];
    const float* sa_rel   = (const float*)d_in[10];
    const float* sa_out_w = (const float*)d_in[11];
    const float* sa_out_b = (const float*)d_in[12];
    const float* ca_in_w  = (const float*)d_in[13];
    const float* ca_in_b  = (const float*)d_in[14];
    const float* ca_out_w = (const float*)d_in[15];
    const float* ca_out_b = (const float*)d_in[16];
    const float* lin1_w   = (const float*)d_in[17];
    const float* lin1_b   = (const float*)d_in[18];
    const float* lin2_w   = (const float*)d_in[19];
    const float* lin2_b   = (const float*)d_in[20];
    const float* ln1_s    = (const float*)d_in[21];
    const float* ln1_b    = (const float*)d_in[22];
    const float* ln2_s    = (const float*)d_in[23];
    const float* ln2_b    = (const float*)d_in[24];
    const float* ln3_s    = (const float*)d_in[25];
    const float* ln3_b    = (const float*)d_in[26];

    const size_t BT = (size_t)Bn * Tn;   // 4096
    const size_t Q  = 1 << 18;           // 256K elems

    // ---- workspace carve-out ----
    char* ws = (char*)d_ws;
    size_t off = 0;
    auto alloc = [&](size_t bytes) -> char* {
        char* p = ws + off;
        off += (bytes + 255) & ~(size_t)255;
        return p;
    };
    unsigned short* xb   = (unsigned short*)alloc(BT * Dn * 2);
    unsigned short* mb   = (unsigned short*)alloc(BT * Dn * 2);
    unsigned short* wall = (unsigned short*)alloc((16 * Q + Ln * HDn * HDn) * 2);
    float*          bqkv = (float*)alloc(3 * Dn * 4);
    unsigned short* qb   = (unsigned short*)alloc(BT * Dn * 2);          // (B,H,T,HD)
    unsigned short* kb   = (unsigned short*)alloc(BT * Dn * 2);          // (B,H,T,HD)
    unsigned short* vtb  = (unsigned short*)alloc(BT * Dn * 2);          // (B,H,HD,T)
    unsigned short* ur   = (unsigned short*)alloc((size_t)Bn * Hn * Ln * Tn * HDn * 2);
    unsigned short* pb   = (unsigned short*)alloc((size_t)Bn * Hn * Tn * Tn * 2); // 32MB probs
    unsigned short* ob   = (unsigned short*)alloc(BT * Dn * 2);
    float*          t2f  = (float*)alloc(BT * Dn * 4);
    float*          x1f  = (float*)alloc(BT * Dn * 4);
    unsigned short* x1b  = (unsigned short*)alloc(BT * Dn * 2);
    float*          x2f  = (float*)alloc(BT * Dn * 4);
    unsigned short* x2b  = (unsigned short*)alloc(BT * Dn * 2);
    unsigned short* hid  = (unsigned short*)alloc(BT * Fn * 2);
    (void)ws_size; (void)in_sizes; (void)n_in; (void)out_size;

    // arena views
    unsigned short* wqkv = wall;
    unsigned short* wsao = wall + 3 * Q;
    unsigned short* wcain = wall + 4 * Q;
    unsigned short* wcao = wall + 7 * Q;
    unsigned short* wlin1 = wall + 8 * Q;
    unsigned short* wlin2 = wall + 12 * Q;
    unsigned short* wrel = wall + 16 * Q;

    auto gemm = [&](const unsigned short* A, const unsigned short* W, const float* bias,
                    void* C, void* C2, void* C3, int M, int N, int K, int lda, int ldw, int ldc,
                    long sA1, long sA2, long sW1, long sW2, long sC1, long sC2,
                    int zdiv, int batches, float alpha, int mode, int relu, int Tp) {
        dim3 g(N / 64, M / 64, batches);
        gemm_bf16<<<g, 256, 0, stream>>>(A, W, bias, C, C2, C3, M, N, K, lda, ldw, ldc,
                                         sA1, sA2, sW1, sW2, sC1, sC2, zdiv,
                                         alpha, mode, relu, Tp);
    };
    // 128x128 tile
    auto gemmBig = [&](const unsigned short* A, const unsigned short* W, const float* bias,
                       void* C, void* C2, void* C3, int M, int N, int K,
                       int lda, int ldw, int ldc, float alpha, int mode, int relu, int Tp) {
        dim3 g(N / 128, M / 128, 1);
        gemmT_bf16<4, 4><<<g, 256, 0, stream>>>(A, W, bias, C, C2, C3, K, lda, ldw, ldc,
                                                alpha, mode, relu, Tp);
    };
    // 128x64 tile (N=512 cases -> 256 blocks = 1/CU)
    auto gemmMed = [&](const unsigned short* A, const unsigned short* W, const float* bias,
                       void* C, void* C2, void* C3, int M, int N, int K,
                       int lda, int ldw, int ldc, float alpha, int mode, int relu, int Tp) {
        dim3 g(N / 64, M / 128, 1);
        gemmT_bf16<4, 2><<<g, 256, 0, stream>>>(A, W, bias, C, C2, C3, K, lda, ldw, ldc,
                                                alpha, mode, relu, Tp);
    };

    // ---- prep ----
    to_rows_bf16<<<dim3((BT * Dn + 255) / 256), 256, 0, stream>>>(tgt, xb, Tn);
    to_rows_bf16<<<dim3((BT * Dn + 255) / 256), 256, 0, stream>>>(memr, mb, Sn);
    conv_all<<<dim3((16 * Q + Ln * HDn * HDn + 3 * Dn + 255) / 256), 256, 0, stream>>>(
        sa_q_w, sa_k_w, sa_v_w, sa_out_w, ca_in_w, ca_out_w, lin1_w, lin2_w, sa_rel,
        sa_q_b, sa_k_b, sa_v_b, wall, bqkv);

    // ---- self-attention ----
    // fused q,k,v: (B,H,T,HD) x2 + v as (B,H,HD,T)
    gemmBig(xb, wqkv, bqkv, qb, kb, vtb, (int)BT, 3 * Dn, Dn, Dn, Dn, 0, 1.0f, 4, 0, Tn);
    // uR[b,h,l] = q[b,h] @ R_l^T  (batched over B*H*L)
    gemm(qb, wrel, nullptr, ur, nullptr, nullptr, Tn, HDn, HDn, HDn, HDn, HDn,
         (long)Tn * HDn, 0, 0, (long)HDn * HDn, (long)Ln * Tn * HDn, (long)Tn * HDn,
         Ln, Bn * Hn * Ln, 1.0f, 1, 0, 0);
    // fused rel-scores + em + scale + pad + softmax -> bf16 P
    relsoft_em<<<dim3(1024), 512, 0, stream>>>(ur, kb, em, pad, pb);
    // O = P @ V
    gemm(pb, vtb, nullptr, ob, nullptr, nullptr, Tn, HDn, Tn, Tn, Tn, Dn,
         (long)Hn * Tn * Tn, (long)Tn * Tn, (long)Hn * HDn * Tn, (long)HDn * Tn,
         (long)Tn * Dn, 64, Hn, Bn * Hn, 1.0f, 1, 0, 0);
    gemmMed(ob, wsao, sa_out_b, t2f, nullptr, nullptr, (int)BT, Dn, Dn, Dn, Dn, Dn,
            1.0f, 0, 0, 0);
    ln_kernel<<<dim3((int)BT), 256, 0, stream>>>(tgt, 1, t2f, ln1_s, ln1_b, x1f, 0, x1b);

    // ---- cross-attention ----
    gemmMed(x1b, wcain, ca_in_b, qb, nullptr, nullptr, (int)BT, Dn, Dn, Dn, Dn, 0,
            1.0f, 2, 0, Tn);
    // fused k,v from memory
    gemmBig(mb, wcain + (size_t)Dn * Dn, ca_in_b + Dn, kb, vtb, nullptr, (int)BT, 2 * Dn, Dn,
            Dn, Dn, 0, 1.0f, 5, 0, Sn);
    // fused qk^T + scale + softmax -> bf16 P
    relsoft_nc<<<dim3(2048), 256, 0, stream>>>(qb, kb, pb);
    gemm(pb, vtb, nullptr, ob, nullptr, nullptr, Tn, HDn, Sn, Sn, Sn, Dn,
         (long)Hn * Tn * Sn, (long)Tn * Sn, (long)Hn * HDn * Sn, (long)HDn * Sn,
         (long)Tn * Dn, 64, Hn, Bn * Hn, 1.0f, 1, 0, 0);
    gemmMed(ob, wcao, ca_out_b, t2f, nullptr, nullptr, (int)BT, Dn, Dn, Dn, Dn, Dn,
            1.0f, 0, 0, 0);
    ln_kernel<<<dim3((int)BT), 256, 0, stream>>>(x1f, 0, t2f, ln2_s, ln2_b, x2f, 0, x2b);

    // ---- FFN ----
    gemmBig(x2b, wlin1, lin1_b, hid, nullptr, nullptr, (int)BT, Fn, Dn, Dn, Dn, Fn,
            1.0f, 1, 1, 0);
    gemmMed(hid, wlin2, lin2_b, t2f, nullptr, nullptr, (int)BT, Dn, Fn, Fn, Fn, Dn,
            1.0f, 0, 0, 0);
    ln_kernel<<<dim3((int)BT), 256, 0, stream>>>(x2f, 0, t2f, ln3_s, ln3_b, (float*)d_out, 1, nullptr);
}